// Round 5
// baseline (283.001 us; speedup 1.0000x reference)
//
#include <hip/hip_runtime.h>
#include <math.h>

#define N_NODES 100000
#define N_EDGES 1600000
#define IN_CH 128
#define HEADS 4
#define HEAD_DIM 16
#define OUT_CH 64
#define NEG_SLOPE 0.2f
#define EPS 1e-8f

// ---- counting-sort CSR build parameters ----
#define NBUCK 391                 // coarse buckets of 256 nodes: (100000+255)/256
#define NBLK1 256                 // pass-1/3 blocks
#define CHUNK (N_EDGES / NBLK1)   // 6250 edges per block (exact)
#define CAP 4608                  // LDS staging bound per bucket (mean 4092 + 8 sigma)

typedef _Float16 f16x8 __attribute__((ext_vector_type(8)));
typedef _Float16 f16x4 __attribute__((ext_vector_type(4)));
typedef float    f32x4 __attribute__((ext_vector_type(4)));

__device__ inline f16x8 cvt8(const float* p) {
    float4 lo = ((const float4*)p)[0];
    float4 hi = ((const float4*)p)[1];
    f16x8 f;
    f[0] = (_Float16)lo.x; f[1] = (_Float16)lo.y;
    f[2] = (_Float16)lo.z; f[3] = (_Float16)lo.w;
    f[4] = (_Float16)hi.x; f[5] = (_Float16)hi.y;
    f[6] = (_Float16)hi.z; f[7] = (_Float16)hi.w;
    return f;
}

// ---------------------------------------------------------------------------
// GEMM via MFMA 16x16x32 f16. Block = 4 waves x 32 nodes = 128 nodes.
// N-tile 4 carries alpha (a.W rows computed inline; cols 0-3 = a_src heads,
// 4-7 = a_dst heads). h is staged through LDS so the global write is
// coalesced f16x8 (the old per-element 2B stores were 32 VMEM instrs/lane).
// ---------------------------------------------------------------------------
__global__ __launch_bounds__(256) void gemm_alpha_kernel(
    const float* __restrict__ x,      // [N_NODES, 128]
    const float* __restrict__ W,      // [64, 128]
    const float* __restrict__ a,      // [1, 4, 32]
    _Float16* __restrict__ h,         // [N_NODES, 64] fp16
    float* __restrict__ alpha_src,    // [N_NODES, 4]
    float* __restrict__ alpha_dst)    // [N_NODES, 4]
{
    __shared__ _Float16 hst[128 * 72];   // stride 72: 16B-aligned rows, 2-way banks

    const int wv = threadIdx.x >> 6;
    const int lane = threadIdx.x & 63;
    const int col = lane & 15;
    const int quad = lane >> 4;
    const int node_base = blockIdx.x * 128 + wv * 32;

    f16x8 bfrag[5][4];
#pragma unroll
    for (int nt = 0; nt < 4; nt++) {
        const float* src = W + (nt * 16 + col) * IN_CH;
#pragma unroll
        for (int ks = 0; ks < 4; ks++)
            bfrag[nt][ks] = cvt8(src + ks * 32 + quad * 8);
    }
    // alpha rows: wsd[row][k] = sum_c a[row-half][c] * W[(hd*16+c)*128 + k]
#pragma unroll
    for (int ks = 0; ks < 4; ks++) {
        f16x8 f = {};
        if (col < 8) {
            int hd = col & 3;
            const float* av = a + hd * 32 + (col >> 2) * 16;   // 0-3: src, 4-7: dst
            const float* wb = W + hd * 16 * IN_CH + ks * 32 + quad * 8;
#pragma unroll
            for (int j = 0; j < 8; j++) {
                float s = 0.f;
#pragma unroll
                for (int c = 0; c < 16; c++)
                    s += av[c] * wb[c * IN_CH + j];
                f[j] = (_Float16)s;
            }
        }
        bfrag[4][ks] = f;
    }

#pragma unroll
    for (int mt = 0; mt < 2; mt++) {
        int row_node = node_base + mt * 16 + col;
        int rn = row_node < N_NODES ? row_node : N_NODES - 1;
        const float* xrow = x + (long long)rn * IN_CH;

        f16x8 afrag[4];
#pragma unroll
        for (int ks = 0; ks < 4; ks++)
            afrag[ks] = cvt8(xrow + ks * 32 + quad * 8);

        f32x4 acc[5];
#pragma unroll
        for (int nt = 0; nt < 5; nt++) {
            f32x4 z = {0.f, 0.f, 0.f, 0.f};
            acc[nt] = z;
        }
#pragma unroll
        for (int ks = 0; ks < 4; ks++)
#pragma unroll
            for (int nt = 0; nt < 5; nt++)
                acc[nt] = __builtin_amdgcn_mfma_f32_16x16x32_f16(
                    afrag[ks], bfrag[nt][ks], acc[nt], 0, 0, 0);

#pragma unroll
        for (int r = 0; r < 4; r++) {
            int nl = wv * 32 + mt * 16 + quad * 4 + r;
#pragma unroll
            for (int nt = 0; nt < 4; nt++)
                hst[nl * 72 + nt * 16 + col] = (_Float16)acc[nt][r];
            int node = node_base + mt * 16 + quad * 4 + r;
            if (node < N_NODES) {
                if (col < 4)      alpha_src[node * HEADS + col]     = acc[4][r];
                else if (col < 8) alpha_dst[node * HEADS + col - 4] = acc[4][r];
            }
        }
    }

    // coalesced copy-out: 128 nodes x 64 ch fp16 = 16KB contiguous per block
    __syncthreads();
    const int bnode = blockIdx.x * 128;
    const int nrem = N_NODES - bnode;
    const int climit = (nrem < 128 ? nrem : 128) << 3;   // f16x8 chunks
    for (int i = threadIdx.x; i < 1024; i += 256) {
        if (i < climit) {
            int node = i >> 3, ch8 = i & 7;
            *(f16x8*)(h + (long long)(bnode + node) * OUT_CH + ch8 * 8) =
                *(const f16x8*)&hst[node * 72 + ch8 * 8];
        }
    }
}

// ---------------------------------------------------------------------------
// CSR build: two-level counting sort. ZERO global atomics.
//   K1 coarse_count : per-block LDS hist over 391 buckets (dst>>8)
//   K2a partial_scan: per-bucket exclusive prefix over the 256 blocks
//   K2b bucket_offs : exclusive scan of bucket totals -> bucketStart
//   K3 coarse_scatter: LDS cursors (absolute) -> tmp[] bucket-sorted,
//                      packed u64 = w<<32 | dloc<<17 | src
//   K4 finalize v2  : SINGLE global read of tmp (staged in LDS), LDS
//                      count+scan -> ptr[], scatter-write csr from LDS.
//                      len>CAP (8-sigma, ~impossible) falls back to 2-pass.
// ---------------------------------------------------------------------------
__global__ __launch_bounds__(256) void coarse_count_kernel(
    const int* __restrict__ ei, int* __restrict__ counts /*[NBUCK][NBLK1]*/)
{
    __shared__ int cnt[NBUCK];
    for (int j = threadIdx.x; j < NBUCK; j += 256) cnt[j] = 0;
    __syncthreads();
    const int base = blockIdx.x * CHUNK;
    for (int i = threadIdx.x; i < CHUNK; i += 256) {
        int d = ei[N_EDGES + base + i];
        atomicAdd(&cnt[d >> 8], 1);          // LDS atomic
    }
    __syncthreads();
    for (int j = threadIdx.x; j < NBUCK; j += 256)
        counts[j * NBLK1 + blockIdx.x] = cnt[j];
}

__global__ __launch_bounds__(256) void partial_scan_kernel(
    int* __restrict__ counts, int* __restrict__ totals)
{
    __shared__ int s[256];
    const int j = blockIdx.x;
    const int t = threadIdx.x;
    int v = counts[j * NBLK1 + t];
    s[t] = v;
    __syncthreads();
    for (int off = 1; off < 256; off <<= 1) {
        int x = (t >= off) ? s[t - off] : 0;
        __syncthreads();
        s[t] += x;
        __syncthreads();
    }
    counts[j * NBLK1 + t] = s[t] - v;        // exclusive partial prefix
    if (t == 255) totals[j] = s[255];
}

__global__ __launch_bounds__(512) void bucket_offsets_kernel(
    const int* __restrict__ totals, int* __restrict__ bucketStart,
    int* __restrict__ ptr)
{
    __shared__ int part[512];
    const int t = threadIdx.x;
    int v = (t < NBUCK) ? totals[t] : 0;
    part[t] = v;
    __syncthreads();
    for (int off = 1; off < 512; off <<= 1) {
        int x = (t >= off) ? part[t - off] : 0;
        __syncthreads();
        part[t] += x;
        __syncthreads();
    }
    if (t < NBUCK) bucketStart[t] = part[t] - v;     // exclusive
    if (t == 0) { bucketStart[NBUCK] = N_EDGES; ptr[N_NODES] = N_EDGES; }
}

__global__ __launch_bounds__(256) void coarse_scatter_kernel(
    const int* __restrict__ ei, const float* __restrict__ ew,
    const int* __restrict__ counts, const int* __restrict__ bucketStart,
    unsigned long long* __restrict__ tmp)
{
    __shared__ int cur[NBUCK];
    const int b = blockIdx.x;
    for (int j = threadIdx.x; j < NBUCK; j += 256)
        cur[j] = bucketStart[j] + counts[j * NBLK1 + b];   // absolute cursor
    __syncthreads();
    const int base = b * CHUNK;
    for (int i = threadIdx.x; i < CHUNK; i += 256) {
        int e = base + i;
        int s = ei[e];
        int d = ei[N_EDGES + e];
        float w = ew[e];
        int pos = atomicAdd(&cur[d >> 8], 1);              // LDS atomic
        unsigned long long pk = ((unsigned long long)__float_as_uint(w) << 32)
                              | ((unsigned)(d & 255) << 17) | (unsigned)s;
        tmp[pos] = pk;   // per-(block,bucket) runs ~128B contiguous
    }
}

__global__ __launch_bounds__(256) void finalize_kernel(
    const unsigned long long* __restrict__ tmp,
    const int* __restrict__ bucketStart,
    long long* __restrict__ csr, int* __restrict__ ptr)
{
    __shared__ int cnt[256];
    __shared__ int offs[256];
    __shared__ unsigned long long stage[CAP];
    const int j = blockIdx.x;
    const int t = threadIdx.x;
    const int beg = bucketStart[j];
    const int end = bucketStart[j + 1];
    const int len = end - beg;

    cnt[t] = 0;
    __syncthreads();

    if (len <= CAP) {
        // ---- fast path: single global read, stage raw bucket in LDS ----
        for (int i = t; i < len; i += 256) {
            unsigned long long pk = __builtin_nontemporal_load(&tmp[beg + i]);
            stage[i] = pk;
            atomicAdd(&cnt[(int)((pk >> 17) & 255)], 1);
        }
        __syncthreads();
        int v = cnt[t];
        for (int off = 1; off < 256; off <<= 1) {   // inclusive scan
            int x = (t >= off) ? cnt[t - off] : 0;
            __syncthreads();
            cnt[t] += x;
            __syncthreads();
        }
        int excl = cnt[t] - v;
        int node = j * 256 + t;
        if (node < N_NODES) ptr[node] = beg + excl;
        offs[t] = excl;
        __syncthreads();
        for (int i = t; i < len; i += 256) {
            unsigned long long pk = stage[i];
            int dloc = (int)((pk >> 17) & 255);
            int pos = atomicAdd(&offs[dloc], 1);
            unsigned long long vv = (pk & 0xFFFFFFFF00000000ull) | (pk & 0x1FFFFull);
            ((unsigned long long*)csr)[beg + pos] = vv;  // 32KB window, L2-combined
        }
    } else {
        // ---- fallback: two-pass from global (statistically unreachable) ----
        for (int i = t; i < len; i += 256) {
            int dloc = (int)((tmp[beg + i] >> 17) & 255);
            atomicAdd(&cnt[dloc], 1);
        }
        __syncthreads();
        int v = cnt[t];
        for (int off = 1; off < 256; off <<= 1) {
            int x = (t >= off) ? cnt[t - off] : 0;
            __syncthreads();
            cnt[t] += x;
            __syncthreads();
        }
        int excl = cnt[t] - v;
        int node = j * 256 + t;
        if (node < N_NODES) ptr[node] = beg + excl;
        offs[t] = excl;
        __syncthreads();
        for (int i = t; i < len; i += 256) {
            unsigned long long pk = tmp[beg + i];
            int dloc = (int)((pk >> 17) & 255);
            int pos = atomicAdd(&offs[dloc], 1);
            unsigned long long vv = (pk & 0xFFFFFFFF00000000ull) | (pk & 0x1FFFFull);
            ((unsigned long long*)csr)[beg + pos] = vv;
        }
    }
}

// ---------------------------------------------------------------------------
// Aggregate v3 (reverted from v4: deeper unroll + nt scalar loads cost
// occupancy 67->52% and split the int2 load into half-utilized stride-8
// dword loads; 46.2 -> 56.0 us. This version is ~5% from the L2-fill
// bound of the random h gather). One wave per dst node, quarter-wave
// edge parallelism.
// ---------------------------------------------------------------------------
__global__ __launch_bounds__(256) void aggregate_kernel(
    const int* __restrict__ ptr,
    const int2* __restrict__ csr,
    const float4* __restrict__ alpha_src4,   // [N_NODES]
    const float4* __restrict__ alpha_dst4,   // [N_NODES]
    const _Float16* __restrict__ h,          // [N_NODES, 64]
    float* __restrict__ out)
{
    __shared__ float4 sev[4][64];   // per-wave ev4 staging
    __shared__ int    ssc[4][64];   // per-wave src staging

    const int wv = threadIdx.x >> 6;
    const int lane = threadIdx.x & 63;
    const int n = blockIdx.x * 4 + wv;
    if (n >= N_NODES) return;
    const int q = lane >> 4;          // quarter 0..3
    const int cg = lane & 15;         // channel group: ch 4*cg..4*cg+3
    const int hsel = cg >> 2;         // head of this channel group

    const int beg = ptr[n];
    const int end = ptr[n + 1];
    const float4 ad4 = alpha_dst4[n];

    float4 acc = make_float4(0.f, 0.f, 0.f, 0.f);
    float denom = 0.f;
    float4* sev_w = sev[wv];
    int* ssc_w = ssc[wv];

    for (int base = beg; base < end; base += 64) {
        int cnt = min(64, end - base);
        int s_l = 0;
        float4 e4 = make_float4(0.f, 0.f, 0.f, 0.f);
        if (lane < cnt) {
            int2 pr = csr[base + lane];
            s_l = pr.x;
            float w = __int_as_float(pr.y);
            float4 as = alpha_src4[s_l];
            float t0 = as.x + ad4.x; t0 = (t0 > 0.f ? t0 : NEG_SLOPE * t0) * w;
            float t1 = as.y + ad4.y; t1 = (t1 > 0.f ? t1 : NEG_SLOPE * t1) * w;
            float t2 = as.z + ad4.z; t2 = (t2 > 0.f ? t2 : NEG_SLOPE * t2) * w;
            float t3 = as.w + ad4.w; t3 = (t3 > 0.f ? t3 : NEG_SLOPE * t3) * w;
            e4 = make_float4(__expf(t0), __expf(t1), __expf(t2), __expf(t3));
        }
        sev_w[lane] = e4;         // intra-wave LDS, no barrier needed
        ssc_w[lane] = s_l;

        int iters = (cnt + 3) >> 2;
        for (int j0 = 0; j0 < iters; j0 += 2) {
            int idx0 = j0 * 4 + q;
            int idx1 = idx0 + 4;          // may pass cnt: contributes zero
            int s0 = ssc_w[idx0];
            int s1 = ssc_w[idx1];
            float ev0 = ((const float*)&sev_w[idx0])[hsel];
            float ev1 = ((const float*)&sev_w[idx1])[hsel];
            f16x4 h0 = *(const f16x4*)(h + s0 * OUT_CH + cg * 4);
            f16x4 h1 = *(const f16x4*)(h + s1 * OUT_CH + cg * 4);
            acc.x += ev0 * (float)h0[0] + ev1 * (float)h1[0];
            acc.y += ev0 * (float)h0[1] + ev1 * (float)h1[1];
            acc.z += ev0 * (float)h0[2] + ev1 * (float)h1[2];
            acc.w += ev0 * (float)h0[3] + ev1 * (float)h1[3];
            denom += ev0 + ev1;
        }
    }

    // combine the 4 quarters (xor butterfly)
    denom += __shfl_xor(denom, 16);
    denom += __shfl_xor(denom, 32);
    acc.x += __shfl_xor(acc.x, 16);  acc.x += __shfl_xor(acc.x, 32);
    acc.y += __shfl_xor(acc.y, 16);  acc.y += __shfl_xor(acc.y, 32);
    acc.z += __shfl_xor(acc.z, 16);  acc.z += __shfl_xor(acc.z, 32);
    acc.w += __shfl_xor(acc.w, 16);  acc.w += __shfl_xor(acc.w, 32);

    if (lane < 16) {
        float inv = 1.f / (denom + EPS);
        float4 r = make_float4(acc.x * inv, acc.y * inv, acc.z * inv, acc.w * inv);
        ((float4*)(out + (long long)n * OUT_CH))[cg] = r;
    }
}

extern "C" void kernel_launch(void* const* d_in, const int* in_sizes, int n_in,
                              void* d_out, int out_size, void* d_ws, size_t ws_size,
                              hipStream_t stream) {
    const float* x  = (const float*)d_in[0];
    const int*   ei = (const int*)d_in[1];     // int32 per harness contract
    const float* ew = (const float*)d_in[2];
    const float* W  = (const float*)d_in[3];
    const float* a  = (const float*)d_in[4];
    float* out = (float*)d_out;

    // workspace layout (all 16B-aligned)
    char* p = (char*)d_ws;
    _Float16* h      = (_Float16*)p; p += (size_t)N_NODES * OUT_CH * 2;   // 12.8 MB
    float* alpha_src = (float*)p;  p += (size_t)N_NODES * HEADS * 4;      // 1.6 MB
    float* alpha_dst = (float*)p;  p += (size_t)N_NODES * HEADS * 4;      // 1.6 MB
    int*   counts    = (int*)p;    p += (size_t)NBUCK * NBLK1 * 4;        // 400 KB
    int*   totals    = (int*)p;    p += (size_t)392 * 4;                  // 1.6 KB
    int*   bstart    = (int*)p;    p += (size_t)392 * 4;                  // 1.6 KB
    int*   ptr       = (int*)p;    p += (size_t)(N_NODES + 4) * 4;        // 0.4 MB
    unsigned long long* tmp = (unsigned long long*)p;
    p += (size_t)N_EDGES * 8;                                             // 12.8 MB
    long long* csr   = (long long*)p;                                     // 12.8 MB

    coarse_count_kernel<<<NBLK1, 256, 0, stream>>>(ei, counts);
    partial_scan_kernel<<<NBUCK, 256, 0, stream>>>(counts, totals);
    bucket_offsets_kernel<<<1, 512, 0, stream>>>(totals, bstart, ptr);
    gemm_alpha_kernel<<<(N_NODES + 127) / 128, 256, 0, stream>>>(x, W, a, h, alpha_src, alpha_dst);
    coarse_scatter_kernel<<<NBLK1, 256, 0, stream>>>(ei, ew, counts, bstart, tmp);
    finalize_kernel<<<NBUCK, 256, 0, stream>>>(tmp, bstart, csr, ptr);
    aggregate_kernel<<<(N_NODES + 3) / 4, 256, 0, stream>>>(
        ptr, (const int2*)csr, (const float4*)alpha_src, (const float4*)alpha_dst, h, out);
}

// Round 6
// 230.264 us; speedup vs baseline: 1.2290x; 1.2290x over previous
//
#include <hip/hip_runtime.h>
#include <math.h>

#define N_NODES 100000
#define N_EDGES 1600000
#define IN_CH 128
#define HEADS 4
#define HEAD_DIM 16
#define OUT_CH 64
#define NEG_SLOPE 0.2f
#define EPS 1e-8f

// ---- counting-sort CSR build parameters ----
#define NBUCK 391                 // coarse buckets of 256 nodes: (100000+255)/256
#define NBLK1 256                 // pass-1/3 blocks
#define CHUNK (N_EDGES / NBLK1)   // 6250 edges per block (exact)
#define CAP 4608                  // LDS staging bound per bucket (mean 4092 + 8 sigma)

typedef _Float16 f16x8 __attribute__((ext_vector_type(8)));
typedef _Float16 f16x4 __attribute__((ext_vector_type(4)));
typedef float    f32x4 __attribute__((ext_vector_type(4)));

// ---------------------------------------------------------------------------
// Prep: wsd[8][128] fp32 — w_s rows 0-3, w_d rows 4-7.
// ---------------------------------------------------------------------------
__global__ __launch_bounds__(128) void wsd_kernel(
    const float* __restrict__ W, const float* __restrict__ a,
    float* __restrict__ wsd)
{
    int k = threadIdx.x;   // 0..127
#pragma unroll
    for (int hd = 0; hd < 4; hd++) {
        float ss = 0.f, dd = 0.f;
#pragma unroll
        for (int c = 0; c < 16; c++) {
            float wv = W[(hd * 16 + c) * IN_CH + k];
            ss += a[hd * 32 + c] * wv;
            dd += a[hd * 32 + 16 + c] * wv;
        }
        wsd[hd * IN_CH + k] = ss;
        wsd[(4 + hd) * IN_CH + k] = dd;
    }
}

__device__ inline f16x8 cvt8(const float* p) {
    float4 lo = ((const float4*)p)[0];
    float4 hi = ((const float4*)p)[1];
    f16x8 f;
    f[0] = (_Float16)lo.x; f[1] = (_Float16)lo.y;
    f[2] = (_Float16)lo.z; f[3] = (_Float16)lo.w;
    f[4] = (_Float16)hi.x; f[5] = (_Float16)hi.y;
    f[6] = (_Float16)hi.z; f[7] = (_Float16)hi.w;
    return f;
}

// ---------------------------------------------------------------------------
// GEMM v3 via MFMA 16x16x32 f16. ONE m-tile (16 nodes) per wave:
// grid 782->1563 blocks (6252 waves = 24/CU available vs 12 before) — the
// old 32-node/wave version was grid+latency-bound (occupancy ~8-12%, x-load
// chain exposed). B-frags are loaded per output-tile (W is L1/L2-hot) so
// register liveness stays low; launch_bounds caps at 128 VGPR = 16 waves/CU.
// N-tile 4 carries alpha (wsd rows; cols 0-3 = a_src heads, 4-7 = a_dst).
// ---------------------------------------------------------------------------
__global__ __launch_bounds__(256, 4) void gemm_alpha_kernel(
    const float* __restrict__ x,      // [N_NODES, 128]
    const float* __restrict__ W,      // [64, 128]
    const float* __restrict__ wsd,    // [8, 128]
    _Float16* __restrict__ h,         // [N_NODES, 64] fp16
    float* __restrict__ alpha_src,    // [N_NODES, 4]
    float* __restrict__ alpha_dst)    // [N_NODES, 4]
{
    const int wv = threadIdx.x >> 6;
    const int lane = threadIdx.x & 63;
    const int col = lane & 15;
    const int quad = lane >> 4;
    const int node_base = blockIdx.x * 64 + wv * 16;

    int row_node = node_base + col;
    int rn = row_node < N_NODES ? row_node : N_NODES - 1;
    const float* xrow = x + (long long)rn * IN_CH;

    f16x8 afrag[4];
#pragma unroll
    for (int ks = 0; ks < 4; ks++)
        afrag[ks] = cvt8(xrow + ks * 32 + quad * 8);

    f32x4 acc[5];
#pragma unroll
    for (int nt = 0; nt < 5; nt++) {
        f32x4 z = {0.f, 0.f, 0.f, 0.f};
        acc[nt] = z;
    }

#pragma unroll
    for (int nt = 0; nt < 5; nt++) {
        const float* src = (nt < 4) ? W + (nt * 16 + col) * IN_CH
                                    : wsd + (col < 8 ? col : 0) * IN_CH;
#pragma unroll
        for (int ks = 0; ks < 4; ks++) {
            f16x8 b = cvt8(src + ks * 32 + quad * 8);
            if (nt == 4 && col >= 8) {
                f16x8 z = {};
                b = z;
            }
            acc[nt] = __builtin_amdgcn_mfma_f32_16x16x32_f16(
                afrag[ks], b, acc[nt], 0, 0, 0);
        }
    }

#pragma unroll
    for (int r = 0; r < 4; r++) {
        int node = node_base + quad * 4 + r;
        if (node < N_NODES) {
#pragma unroll
            for (int nt = 0; nt < 4; nt++)
                h[(long long)node * OUT_CH + nt * 16 + col] = (_Float16)acc[nt][r];
            if (col < 4)      alpha_src[node * HEADS + col]     = acc[4][r];
            else if (col < 8) alpha_dst[node * HEADS + col - 4] = acc[4][r];
        }
    }
}

// ---------------------------------------------------------------------------
// CSR build: two-level counting sort. ZERO global atomics.
//   K1 coarse_count : per-block LDS hist over 391 buckets (dst>>8)
//   K2a partial_scan: per-bucket exclusive prefix over the 256 blocks
//   K2b bucket_offs : exclusive scan of bucket totals -> bucketStart
//   K3 coarse_scatter: LDS cursors (absolute) -> tmp[] bucket-sorted,
//                      packed u64 = w<<32 | dloc<<17 | src
//   K4 finalize v2  : SINGLE global read of tmp (staged in LDS), LDS
//                      count+scan -> ptr[], scatter-write csr from LDS.
//                      len>CAP (8-sigma, ~impossible) falls back to 2-pass.
// ---------------------------------------------------------------------------
__global__ __launch_bounds__(256) void coarse_count_kernel(
    const int* __restrict__ ei, int* __restrict__ counts /*[NBUCK][NBLK1]*/)
{
    __shared__ int cnt[NBUCK];
    for (int j = threadIdx.x; j < NBUCK; j += 256) cnt[j] = 0;
    __syncthreads();
    const int base = blockIdx.x * CHUNK;
    for (int i = threadIdx.x; i < CHUNK; i += 256) {
        int d = ei[N_EDGES + base + i];
        atomicAdd(&cnt[d >> 8], 1);          // LDS atomic
    }
    __syncthreads();
    for (int j = threadIdx.x; j < NBUCK; j += 256)
        counts[j * NBLK1 + blockIdx.x] = cnt[j];
}

__global__ __launch_bounds__(256) void partial_scan_kernel(
    int* __restrict__ counts, int* __restrict__ totals)
{
    __shared__ int s[256];
    const int j = blockIdx.x;
    const int t = threadIdx.x;
    int v = counts[j * NBLK1 + t];
    s[t] = v;
    __syncthreads();
    for (int off = 1; off < 256; off <<= 1) {
        int x = (t >= off) ? s[t - off] : 0;
        __syncthreads();
        s[t] += x;
        __syncthreads();
    }
    counts[j * NBLK1 + t] = s[t] - v;        // exclusive partial prefix
    if (t == 255) totals[j] = s[255];
}

__global__ __launch_bounds__(512) void bucket_offsets_kernel(
    const int* __restrict__ totals, int* __restrict__ bucketStart,
    int* __restrict__ ptr)
{
    __shared__ int part[512];
    const int t = threadIdx.x;
    int v = (t < NBUCK) ? totals[t] : 0;
    part[t] = v;
    __syncthreads();
    for (int off = 1; off < 512; off <<= 1) {
        int x = (t >= off) ? part[t - off] : 0;
        __syncthreads();
        part[t] += x;
        __syncthreads();
    }
    if (t < NBUCK) bucketStart[t] = part[t] - v;     // exclusive
    if (t == 0) { bucketStart[NBUCK] = N_EDGES; ptr[N_NODES] = N_EDGES; }
}

__global__ __launch_bounds__(256) void coarse_scatter_kernel(
    const int* __restrict__ ei, const float* __restrict__ ew,
    const int* __restrict__ counts, const int* __restrict__ bucketStart,
    unsigned long long* __restrict__ tmp)
{
    __shared__ int cur[NBUCK];
    const int b = blockIdx.x;
    for (int j = threadIdx.x; j < NBUCK; j += 256)
        cur[j] = bucketStart[j] + counts[j * NBLK1 + b];   // absolute cursor
    __syncthreads();
    const int base = b * CHUNK;
    for (int i = threadIdx.x; i < CHUNK; i += 256) {
        int e = base + i;
        int s = ei[e];
        int d = ei[N_EDGES + e];
        float w = ew[e];
        int pos = atomicAdd(&cur[d >> 8], 1);              // LDS atomic
        unsigned long long pk = ((unsigned long long)__float_as_uint(w) << 32)
                              | ((unsigned)(d & 255) << 17) | (unsigned)s;
        tmp[pos] = pk;   // per-(block,bucket) runs ~128B contiguous
    }
}

__global__ __launch_bounds__(256) void finalize_kernel(
    const unsigned long long* __restrict__ tmp,
    const int* __restrict__ bucketStart,
    long long* __restrict__ csr, int* __restrict__ ptr)
{
    __shared__ int cnt[256];
    __shared__ int offs[256];
    __shared__ unsigned long long stage[CAP];
    const int j = blockIdx.x;
    const int t = threadIdx.x;
    const int beg = bucketStart[j];
    const int end = bucketStart[j + 1];
    const int len = end - beg;

    cnt[t] = 0;
    __syncthreads();

    if (len <= CAP) {
        // ---- fast path: single global read, stage raw bucket in LDS ----
        for (int i = t; i < len; i += 256) {
            unsigned long long pk = __builtin_nontemporal_load(&tmp[beg + i]);
            stage[i] = pk;
            atomicAdd(&cnt[(int)((pk >> 17) & 255)], 1);
        }
        __syncthreads();
        int v = cnt[t];
        for (int off = 1; off < 256; off <<= 1) {   // inclusive scan
            int x = (t >= off) ? cnt[t - off] : 0;
            __syncthreads();
            cnt[t] += x;
            __syncthreads();
        }
        int excl = cnt[t] - v;
        int node = j * 256 + t;
        if (node < N_NODES) ptr[node] = beg + excl;
        offs[t] = excl;
        __syncthreads();
        for (int i = t; i < len; i += 256) {
            unsigned long long pk = stage[i];
            int dloc = (int)((pk >> 17) & 255);
            int pos = atomicAdd(&offs[dloc], 1);
            unsigned long long vv = (pk & 0xFFFFFFFF00000000ull) | (pk & 0x1FFFFull);
            ((unsigned long long*)csr)[beg + pos] = vv;  // 32KB window, L2-combined
        }
    } else {
        // ---- fallback: two-pass from global (statistically unreachable) ----
        for (int i = t; i < len; i += 256) {
            int dloc = (int)((tmp[beg + i] >> 17) & 255);
            atomicAdd(&cnt[dloc], 1);
        }
        __syncthreads();
        int v = cnt[t];
        for (int off = 1; off < 256; off <<= 1) {
            int x = (t >= off) ? cnt[t - off] : 0;
            __syncthreads();
            cnt[t] += x;
            __syncthreads();
        }
        int excl = cnt[t] - v;
        int node = j * 256 + t;
        if (node < N_NODES) ptr[node] = beg + excl;
        offs[t] = excl;
        __syncthreads();
        for (int i = t; i < len; i += 256) {
            unsigned long long pk = tmp[beg + i];
            int dloc = (int)((pk >> 17) & 255);
            int pos = atomicAdd(&offs[dloc], 1);
            unsigned long long vv = (pk & 0xFFFFFFFF00000000ull) | (pk & 0x1FFFFull);
            ((unsigned long long*)csr)[beg + pos] = vv;
        }
    }
}

// ---------------------------------------------------------------------------
// Aggregate v3 (best known: 46.2 us, ~5% off the L2-fill bound of the
// random h gather; v4's deeper unroll cost occupancy and regressed).
// One wave per dst node, quarter-wave edge parallelism.
// ---------------------------------------------------------------------------
__global__ __launch_bounds__(256) void aggregate_kernel(
    const int* __restrict__ ptr,
    const int2* __restrict__ csr,
    const float4* __restrict__ alpha_src4,   // [N_NODES]
    const float4* __restrict__ alpha_dst4,   // [N_NODES]
    const _Float16* __restrict__ h,          // [N_NODES, 64]
    float* __restrict__ out)
{
    __shared__ float4 sev[4][64];   // per-wave ev4 staging
    __shared__ int    ssc[4][64];   // per-wave src staging

    const int wv = threadIdx.x >> 6;
    const int lane = threadIdx.x & 63;
    const int n = blockIdx.x * 4 + wv;
    if (n >= N_NODES) return;
    const int q = lane >> 4;          // quarter 0..3
    const int cg = lane & 15;         // channel group: ch 4*cg..4*cg+3
    const int hsel = cg >> 2;         // head of this channel group

    const int beg = ptr[n];
    const int end = ptr[n + 1];
    const float4 ad4 = alpha_dst4[n];

    float4 acc = make_float4(0.f, 0.f, 0.f, 0.f);
    float denom = 0.f;
    float4* sev_w = sev[wv];
    int* ssc_w = ssc[wv];

    for (int base = beg; base < end; base += 64) {
        int cnt = min(64, end - base);
        int s_l = 0;
        float4 e4 = make_float4(0.f, 0.f, 0.f, 0.f);
        if (lane < cnt) {
            int2 pr = csr[base + lane];
            s_l = pr.x;
            float w = __int_as_float(pr.y);
            float4 as = alpha_src4[s_l];
            float t0 = as.x + ad4.x; t0 = (t0 > 0.f ? t0 : NEG_SLOPE * t0) * w;
            float t1 = as.y + ad4.y; t1 = (t1 > 0.f ? t1 : NEG_SLOPE * t1) * w;
            float t2 = as.z + ad4.z; t2 = (t2 > 0.f ? t2 : NEG_SLOPE * t2) * w;
            float t3 = as.w + ad4.w; t3 = (t3 > 0.f ? t3 : NEG_SLOPE * t3) * w;
            e4 = make_float4(__expf(t0), __expf(t1), __expf(t2), __expf(t3));
        }
        sev_w[lane] = e4;         // intra-wave LDS, no barrier needed
        ssc_w[lane] = s_l;

        int iters = (cnt + 3) >> 2;
        for (int j0 = 0; j0 < iters; j0 += 2) {
            int idx0 = j0 * 4 + q;
            int idx1 = idx0 + 4;          // may pass cnt: contributes zero
            int s0 = ssc_w[idx0];
            int s1 = ssc_w[idx1];
            float ev0 = ((const float*)&sev_w[idx0])[hsel];
            float ev1 = ((const float*)&sev_w[idx1])[hsel];
            f16x4 h0 = *(const f16x4*)(h + s0 * OUT_CH + cg * 4);
            f16x4 h1 = *(const f16x4*)(h + s1 * OUT_CH + cg * 4);
            acc.x += ev0 * (float)h0[0] + ev1 * (float)h1[0];
            acc.y += ev0 * (float)h0[1] + ev1 * (float)h1[1];
            acc.z += ev0 * (float)h0[2] + ev1 * (float)h1[2];
            acc.w += ev0 * (float)h0[3] + ev1 * (float)h1[3];
            denom += ev0 + ev1;
        }
    }

    // combine the 4 quarters (xor butterfly)
    denom += __shfl_xor(denom, 16);
    denom += __shfl_xor(denom, 32);
    acc.x += __shfl_xor(acc.x, 16);  acc.x += __shfl_xor(acc.x, 32);
    acc.y += __shfl_xor(acc.y, 16);  acc.y += __shfl_xor(acc.y, 32);
    acc.z += __shfl_xor(acc.z, 16);  acc.z += __shfl_xor(acc.z, 32);
    acc.w += __shfl_xor(acc.w, 16);  acc.w += __shfl_xor(acc.w, 32);

    if (lane < 16) {
        float inv = 1.f / (denom + EPS);
        float4 r = make_float4(acc.x * inv, acc.y * inv, acc.z * inv, acc.w * inv);
        ((float4*)(out + (long long)n * OUT_CH))[cg] = r;
    }
}

extern "C" void kernel_launch(void* const* d_in, const int* in_sizes, int n_in,
                              void* d_out, int out_size, void* d_ws, size_t ws_size,
                              hipStream_t stream) {
    const float* x  = (const float*)d_in[0];
    const int*   ei = (const int*)d_in[1];     // int32 per harness contract
    const float* ew = (const float*)d_in[2];
    const float* W  = (const float*)d_in[3];
    const float* a  = (const float*)d_in[4];
    float* out = (float*)d_out;

    // workspace layout (all 16B-aligned)
    char* p = (char*)d_ws;
    _Float16* h      = (_Float16*)p; p += (size_t)N_NODES * OUT_CH * 2;   // 12.8 MB
    float* alpha_src = (float*)p;  p += (size_t)N_NODES * HEADS * 4;      // 1.6 MB
    float* alpha_dst = (float*)p;  p += (size_t)N_NODES * HEADS * 4;      // 1.6 MB
    float* wsd       = (float*)p;  p += (size_t)8 * IN_CH * 4;            // 4 KB
    int*   counts    = (int*)p;    p += (size_t)NBUCK * NBLK1 * 4;        // 400 KB
    int*   totals    = (int*)p;    p += (size_t)392 * 4;                  // 1.6 KB
    int*   bstart    = (int*)p;    p += (size_t)392 * 4;                  // 1.6 KB
    int*   ptr       = (int*)p;    p += (size_t)(N_NODES + 4) * 4;        // 0.4 MB
    unsigned long long* tmp = (unsigned long long*)p;
    p += (size_t)N_EDGES * 8;                                             // 12.8 MB
    long long* csr   = (long long*)p;                                     // 12.8 MB

    wsd_kernel<<<1, 128, 0, stream>>>(W, a, wsd);
    coarse_count_kernel<<<NBLK1, 256, 0, stream>>>(ei, counts);
    partial_scan_kernel<<<NBUCK, 256, 0, stream>>>(counts, totals);
    bucket_offsets_kernel<<<1, 512, 0, stream>>>(totals, bstart, ptr);
    gemm_alpha_kernel<<<(N_NODES + 63) / 64, 256, 0, stream>>>(x, W, wsd, h, alpha_src, alpha_dst);
    coarse_scatter_kernel<<<NBLK1, 256, 0, stream>>>(ei, ew, counts, bstart, tmp);
    finalize_kernel<<<NBUCK, 256, 0, stream>>>(tmp, bstart, csr, ptr);
    aggregate_kernel<<<(N_NODES + 3) / 4, 256, 0, stream>>>(
        ptr, (const int2*)csr, (const float4*)alpha_src, (const float4*)alpha_dst, h, out);
}

// Round 7
// 215.172 us; speedup vs baseline: 1.3152x; 1.0701x over previous
//
#include <hip/hip_runtime.h>
#include <math.h>

#define N_NODES 100000
#define N_EDGES 1600000
#define IN_CH 128
#define HEADS 4
#define HEAD_DIM 16
#define OUT_CH 64
#define NEG_SLOPE 0.2f
#define EPS 1e-8f

// ---- counting-sort CSR build parameters ----
#define NBUCK 391                 // coarse buckets of 256 nodes: (100000+255)/256
#define NBLK1 256                 // fused pass blocks
#define CHUNK (N_EDGES / NBLK1)   // 6250 edges per block (exact)
#define CAPG 4608                 // static per-bucket region (mean 4092 + 8 sigma)
#define CAP CAPG

typedef _Float16 f16x8 __attribute__((ext_vector_type(8)));
typedef _Float16 f16x4 __attribute__((ext_vector_type(4)));
typedef float    f32x4 __attribute__((ext_vector_type(4)));

// ---------------------------------------------------------------------------
// Prep: wsd[8][128] fp32 — w_s rows 0-3, w_d rows 4-7.
// ---------------------------------------------------------------------------
__global__ __launch_bounds__(128) void wsd_kernel(
    const float* __restrict__ W, const float* __restrict__ a,
    float* __restrict__ wsd)
{
    int k = threadIdx.x;   // 0..127
#pragma unroll
    for (int hd = 0; hd < 4; hd++) {
        float ss = 0.f, dd = 0.f;
#pragma unroll
        for (int c = 0; c < 16; c++) {
            float wv = W[(hd * 16 + c) * IN_CH + k];
            ss += a[hd * 32 + c] * wv;
            dd += a[hd * 32 + 16 + c] * wv;
        }
        wsd[hd * IN_CH + k] = ss;
        wsd[(4 + hd) * IN_CH + k] = dd;
    }
}

__device__ inline f16x8 cvt8(const float* p) {
    float4 lo = ((const float4*)p)[0];
    float4 hi = ((const float4*)p)[1];
    f16x8 f;
    f[0] = (_Float16)lo.x; f[1] = (_Float16)lo.y;
    f[2] = (_Float16)lo.z; f[3] = (_Float16)lo.w;
    f[4] = (_Float16)hi.x; f[5] = (_Float16)hi.y;
    f[6] = (_Float16)hi.z; f[7] = (_Float16)hi.w;
    return f;
}

// ---------------------------------------------------------------------------
// GEMM v5 = R2 structure (128 nodes/block, bfrag held, 2 m-tiles amortize
// the B load+convert) + LDS-staged coalesced h epilogue (R2's defect was
// 16 scalar 2B h-stores per lane per m-tile; now 4x dwordx4 per lane).
// N-tile 4 carries alpha (wsd rows; cols 0-3 = a_src heads, 4-7 = a_dst).
// ---------------------------------------------------------------------------
__global__ __launch_bounds__(256) void gemm_alpha_kernel(
    const float* __restrict__ x,      // [N_NODES, 128]
    const float* __restrict__ W,      // [64, 128]
    const float* __restrict__ wsd,    // [8, 128]
    _Float16* __restrict__ h,         // [N_NODES, 64] fp16
    float* __restrict__ alpha_src,    // [N_NODES, 4]
    float* __restrict__ alpha_dst)    // [N_NODES, 4]
{
    __shared__ _Float16 hst[128 * 72];   // stride 72: 16B rows, conflicts ~nil (R5)

    const int wv = threadIdx.x >> 6;
    const int lane = threadIdx.x & 63;
    const int col = lane & 15;
    const int quad = lane >> 4;
    const int node_base = blockIdx.x * 128 + wv * 32;

    f16x8 bfrag[5][4];
#pragma unroll
    for (int nt = 0; nt < 4; nt++) {
        const float* src = W + (nt * 16 + col) * IN_CH;
#pragma unroll
        for (int ks = 0; ks < 4; ks++)
            bfrag[nt][ks] = cvt8(src + ks * 32 + quad * 8);
    }
    {
        const float* src = wsd + (col < 8 ? col : 0) * IN_CH;
#pragma unroll
        for (int ks = 0; ks < 4; ks++) {
            f16x8 f = cvt8(src + ks * 32 + quad * 8);
            if (col >= 8) {
                f16x8 z = {};
                f = z;
            }
            bfrag[4][ks] = f;
        }
    }

#pragma unroll
    for (int mt = 0; mt < 2; mt++) {
        int row_node = node_base + mt * 16 + col;
        int rn = row_node < N_NODES ? row_node : N_NODES - 1;
        const float* xrow = x + (long long)rn * IN_CH;

        f16x8 afrag[4];
#pragma unroll
        for (int ks = 0; ks < 4; ks++)
            afrag[ks] = cvt8(xrow + ks * 32 + quad * 8);

        f32x4 acc[5];
#pragma unroll
        for (int nt = 0; nt < 5; nt++) {
            f32x4 z = {0.f, 0.f, 0.f, 0.f};
            acc[nt] = z;
        }
#pragma unroll
        for (int ks = 0; ks < 4; ks++)
#pragma unroll
            for (int nt = 0; nt < 5; nt++)
                acc[nt] = __builtin_amdgcn_mfma_f32_16x16x32_f16(
                    afrag[ks], bfrag[nt][ks], acc[nt], 0, 0, 0);

#pragma unroll
        for (int r = 0; r < 4; r++) {
            int nl = wv * 32 + mt * 16 + quad * 4 + r;
#pragma unroll
            for (int nt = 0; nt < 4; nt++)
                hst[nl * 72 + nt * 16 + col] = (_Float16)acc[nt][r];
            int node = node_base + mt * 16 + quad * 4 + r;
            if (node < N_NODES) {
                if (col < 4)      alpha_src[node * HEADS + col]     = acc[4][r];
                else if (col < 8) alpha_dst[node * HEADS + col - 4] = acc[4][r];
            }
        }
    }

    // coalesced copy-out: 128 nodes x 64 ch fp16, 16B per lane
    __syncthreads();
    const int bnode = blockIdx.x * 128;
    const int nrem = N_NODES - bnode;
    const int climit = (nrem < 128 ? nrem : 128) << 3;   // f16x8 chunks
    for (int i = threadIdx.x; i < 1024; i += 256) {
        if (i < climit) {
            int node = i >> 3, ch8 = i & 7;
            *(f16x8*)(h + (long long)(bnode + node) * OUT_CH + ch8 * 8) =
                *(const f16x8*)&hst[node * 72 + ch8 * 8];
        }
    }
}

// ---------------------------------------------------------------------------
// CSR build v3: fused count+scatter with STATIC per-bucket regions.
//   One kernel: LDS hist over 391 buckets (dst staged in LDS), then ONE
//   global atomicAdd per (block,bucket) to reserve space (100K atomics
//   total ~ 4us at the 25G/s memory-side rate -- fine at this scale; the
//   fatal case was 1.6M), then LDS-cursor scatter into tmp[j*CAPG + ...].
//   Eliminates the 3-pass 400KB counts scan, a 6.4MB ei.dst re-read, and
//   2 launches. Then:
//   bucket_offs : exclusive scan of gcur -> bucketStart (csr base per bucket)
//   finalize    : per-bucket LDS count/scan -> ptr; LDS-staged coalesced
//                 read of tmp region, scatter-write csr within 32KB window.
// ---------------------------------------------------------------------------
__global__ __launch_bounds__(256) void fused_count_scatter_kernel(
    const int* __restrict__ ei, const float* __restrict__ ew,
    int* __restrict__ gcur,                 // [NBUCK] zeroed cursors
    unsigned long long* __restrict__ tmp)   // [NBUCK][CAPG]
{
    __shared__ int cnt[NBUCK];      // hist, then absolute cursors
    __shared__ int dbuf[CHUNK];     // 25000 B staged dst
    for (int j = threadIdx.x; j < NBUCK; j += 256) cnt[j] = 0;
    __syncthreads();
    const int base = blockIdx.x * CHUNK;
    for (int i = threadIdx.x; i < CHUNK; i += 256) {
        int d = ei[N_EDGES + base + i];
        dbuf[i] = d;
        atomicAdd(&cnt[d >> 8], 1);          // LDS atomic
    }
    __syncthreads();
    for (int j = threadIdx.x; j < NBUCK; j += 256) {
        int c = cnt[j];
        int b = (c > 0) ? atomicAdd(&gcur[j], c) : 0;   // global reserve
        cnt[j] = j * CAPG + b;               // absolute cursor into tmp
    }
    __syncthreads();
    for (int i = threadIdx.x; i < CHUNK; i += 256) {
        int e = base + i;
        int d = dbuf[i];
        int s = ei[e];
        float w = ew[e];
        int pos = atomicAdd(&cnt[d >> 8], 1);            // LDS atomic
        unsigned long long pk = ((unsigned long long)__float_as_uint(w) << 32)
                              | ((unsigned)(d & 255) << 17) | (unsigned)s;
        tmp[pos] = pk;   // per-(block,bucket) runs ~128B contiguous
    }
}

__global__ __launch_bounds__(512) void bucket_offsets_kernel(
    const int* __restrict__ gcur, int* __restrict__ bucketStart,
    int* __restrict__ ptr)
{
    __shared__ int part[512];
    const int t = threadIdx.x;
    int v = (t < NBUCK) ? gcur[t] : 0;
    part[t] = v;
    __syncthreads();
    for (int off = 1; off < 512; off <<= 1) {
        int x = (t >= off) ? part[t - off] : 0;
        __syncthreads();
        part[t] += x;
        __syncthreads();
    }
    if (t < NBUCK) bucketStart[t] = part[t] - v;     // exclusive
    if (t == 0) { bucketStart[NBUCK] = N_EDGES; ptr[N_NODES] = N_EDGES; }
}

__global__ __launch_bounds__(256) void finalize_kernel(
    const unsigned long long* __restrict__ tmp,
    const int* __restrict__ gcur,
    const int* __restrict__ bucketStart,
    long long* __restrict__ csr, int* __restrict__ ptr)
{
    __shared__ int cnt[256];
    __shared__ int offs[256];
    __shared__ unsigned long long stage[CAP];
    const int j = blockIdx.x;
    const int t = threadIdx.x;
    const int beg = bucketStart[j];
    const int len = gcur[j];
    const unsigned long long* src = tmp + (size_t)j * CAPG;

    cnt[t] = 0;
    __syncthreads();

    // single global read, stage raw bucket in LDS (len <= CAPG physically)
    for (int i = t; i < len; i += 256) {
        unsigned long long pk = __builtin_nontemporal_load(&src[i]);
        stage[i] = pk;
        atomicAdd(&cnt[(int)((pk >> 17) & 255)], 1);
    }
    __syncthreads();
    int v = cnt[t];
    for (int off = 1; off < 256; off <<= 1) {   // inclusive scan
        int x = (t >= off) ? cnt[t - off] : 0;
        __syncthreads();
        cnt[t] += x;
        __syncthreads();
    }
    int excl = cnt[t] - v;
    int node = j * 256 + t;
    if (node < N_NODES) ptr[node] = beg + excl;
    offs[t] = excl;
    __syncthreads();
    for (int i = t; i < len; i += 256) {
        unsigned long long pk = stage[i];
        int dloc = (int)((pk >> 17) & 255);
        int pos = atomicAdd(&offs[dloc], 1);
        unsigned long long vv = (pk & 0xFFFFFFFF00000000ull) | (pk & 0x1FFFFull);
        ((unsigned long long*)csr)[beg + pos] = vv;  // 32KB window, L2-combined
    }
}

// ---------------------------------------------------------------------------
// Aggregate v3 (best known: ~46 us, ~5% off the L2-fill bound of the
// random h gather; v4's deeper unroll cost occupancy and regressed).
// One wave per dst node, quarter-wave edge parallelism.
// ---------------------------------------------------------------------------
__global__ __launch_bounds__(256) void aggregate_kernel(
    const int* __restrict__ ptr,
    const int2* __restrict__ csr,
    const float4* __restrict__ alpha_src4,   // [N_NODES]
    const float4* __restrict__ alpha_dst4,   // [N_NODES]
    const _Float16* __restrict__ h,          // [N_NODES, 64]
    float* __restrict__ out)
{
    __shared__ float4 sev[4][64];   // per-wave ev4 staging
    __shared__ int    ssc[4][64];   // per-wave src staging

    const int wv = threadIdx.x >> 6;
    const int lane = threadIdx.x & 63;
    const int n = blockIdx.x * 4 + wv;
    if (n >= N_NODES) return;
    const int q = lane >> 4;          // quarter 0..3
    const int cg = lane & 15;         // channel group: ch 4*cg..4*cg+3
    const int hsel = cg >> 2;         // head of this channel group

    const int beg = ptr[n];
    const int end = ptr[n + 1];
    const float4 ad4 = alpha_dst4[n];

    float4 acc = make_float4(0.f, 0.f, 0.f, 0.f);
    float denom = 0.f;
    float4* sev_w = sev[wv];
    int* ssc_w = ssc[wv];

    for (int base = beg; base < end; base += 64) {
        int cnt = min(64, end - base);
        int s_l = 0;
        float4 e4 = make_float4(0.f, 0.f, 0.f, 0.f);
        if (lane < cnt) {
            int2 pr = csr[base + lane];
            s_l = pr.x;
            float w = __int_as_float(pr.y);
            float4 as = alpha_src4[s_l];
            float t0 = as.x + ad4.x; t0 = (t0 > 0.f ? t0 : NEG_SLOPE * t0) * w;
            float t1 = as.y + ad4.y; t1 = (t1 > 0.f ? t1 : NEG_SLOPE * t1) * w;
            float t2 = as.z + ad4.z; t2 = (t2 > 0.f ? t2 : NEG_SLOPE * t2) * w;
            float t3 = as.w + ad4.w; t3 = (t3 > 0.f ? t3 : NEG_SLOPE * t3) * w;
            e4 = make_float4(__expf(t0), __expf(t1), __expf(t2), __expf(t3));
        }
        sev_w[lane] = e4;         // intra-wave LDS, no barrier needed
        ssc_w[lane] = s_l;

        int iters = (cnt + 3) >> 2;
        for (int j0 = 0; j0 < iters; j0 += 2) {
            int idx0 = j0 * 4 + q;
            int idx1 = idx0 + 4;          // may pass cnt: contributes zero
            int s0 = ssc_w[idx0];
            int s1 = ssc_w[idx1];
            float ev0 = ((const float*)&sev_w[idx0])[hsel];
            float ev1 = ((const float*)&sev_w[idx1])[hsel];
            f16x4 h0 = *(const f16x4*)(h + s0 * OUT_CH + cg * 4);
            f16x4 h1 = *(const f16x4*)(h + s1 * OUT_CH + cg * 4);
            acc.x += ev0 * (float)h0[0] + ev1 * (float)h1[0];
            acc.y += ev0 * (float)h0[1] + ev1 * (float)h1[1];
            acc.z += ev0 * (float)h0[2] + ev1 * (float)h1[2];
            acc.w += ev0 * (float)h0[3] + ev1 * (float)h1[3];
            denom += ev0 + ev1;
        }
    }

    // combine the 4 quarters (xor butterfly)
    denom += __shfl_xor(denom, 16);
    denom += __shfl_xor(denom, 32);
    acc.x += __shfl_xor(acc.x, 16);  acc.x += __shfl_xor(acc.x, 32);
    acc.y += __shfl_xor(acc.y, 16);  acc.y += __shfl_xor(acc.y, 32);
    acc.z += __shfl_xor(acc.z, 16);  acc.z += __shfl_xor(acc.z, 32);
    acc.w += __shfl_xor(acc.w, 16);  acc.w += __shfl_xor(acc.w, 32);

    if (lane < 16) {
        float inv = 1.f / (denom + EPS);
        float4 r = make_float4(acc.x * inv, acc.y * inv, acc.z * inv, acc.w * inv);
        ((float4*)(out + (long long)n * OUT_CH))[cg] = r;
    }
}

extern "C" void kernel_launch(void* const* d_in, const int* in_sizes, int n_in,
                              void* d_out, int out_size, void* d_ws, size_t ws_size,
                              hipStream_t stream) {
    const float* x  = (const float*)d_in[0];
    const int*   ei = (const int*)d_in[1];     // int32 per harness contract
    const float* ew = (const float*)d_in[2];
    const float* W  = (const float*)d_in[3];
    const float* a  = (const float*)d_in[4];
    float* out = (float*)d_out;

    // workspace layout (all 16B-aligned); total ~43.7 MB
    char* p = (char*)d_ws;
    _Float16* h      = (_Float16*)p; p += (size_t)N_NODES * OUT_CH * 2;   // 12.8 MB
    float* alpha_src = (float*)p;  p += (size_t)N_NODES * HEADS * 4;      // 1.6 MB
    float* alpha_dst = (float*)p;  p += (size_t)N_NODES * HEADS * 4;      // 1.6 MB
    float* wsd       = (float*)p;  p += (size_t)8 * IN_CH * 4;            // 4 KB
    int*   gcur      = (int*)p;    p += (size_t)392 * 4;                  // 1.6 KB
    int*   bstart    = (int*)p;    p += (size_t)392 * 4;                  // 1.6 KB
    int*   ptr       = (int*)p;    p += (size_t)(N_NODES + 4) * 4;        // 0.4 MB
    unsigned long long* tmp = (unsigned long long*)p;
    p += (size_t)NBUCK * CAPG * 8;                                        // 14.4 MB
    long long* csr   = (long long*)p;                                     // 12.8 MB

    hipMemsetAsync(gcur, 0, 392 * sizeof(int), stream);

    wsd_kernel<<<1, 128, 0, stream>>>(W, a, wsd);
    fused_count_scatter_kernel<<<NBLK1, 256, 0, stream>>>(ei, ew, gcur, tmp);
    bucket_offsets_kernel<<<1, 512, 0, stream>>>(gcur, bstart, ptr);
    gemm_alpha_kernel<<<(N_NODES + 127) / 128, 256, 0, stream>>>(x, W, wsd, h, alpha_src, alpha_dst);
    finalize_kernel<<<NBUCK, 256, 0, stream>>>(tmp, gcur, bstart, csr, ptr);
    aggregate_kernel<<<(N_NODES + 3) / 4, 256, 0, stream>>>(
        ptr, (const int2*)csr, (const float4*)alpha_src, (const float4*)alpha_dst, h, out);
}

// Round 8
// 210.995 us; speedup vs baseline: 1.3413x; 1.0198x over previous
//
#include <hip/hip_runtime.h>
#include <math.h>

#define N_NODES 100000
#define N_EDGES 1600000
#define IN_CH 128
#define HEADS 4
#define HEAD_DIM 16
#define OUT_CH 64
#define NEG_SLOPE 0.2f
#define EPS 1e-8f

// ---- counting-sort CSR build parameters ----
#define NBUCK 391                 // coarse buckets of 256 nodes: (100000+255)/256
#define NBLK1 512                 // fused pass blocks (2/CU: 8 waves/CU TLP)
#define CHUNK (N_EDGES / NBLK1)   // 3125 edges per block (exact)
#define CAPG 4608                 // static per-bucket region (mean 4092 + 8 sigma)
#define CAP CAPG

typedef _Float16 f16x8 __attribute__((ext_vector_type(8)));
typedef _Float16 f16x4 __attribute__((ext_vector_type(4)));
typedef float    f32x4 __attribute__((ext_vector_type(4)));

// ---------------------------------------------------------------------------
// Prep: Wh[72][128] f16 — rows 0-63 = (f16)W, rows 64-67 = w_s, 68-71 = w_d.
// One-time convert so gemm loads f16 directly (no per-block f32 load + cvt).
// ---------------------------------------------------------------------------
__global__ __launch_bounds__(128) void prep16_kernel(
    const float* __restrict__ W, const float* __restrict__ a,
    _Float16* __restrict__ Wh)
{
    int k = threadIdx.x;   // 0..127
#pragma unroll
    for (int r = 0; r < 64; r++)
        Wh[r * IN_CH + k] = (_Float16)W[r * IN_CH + k];
#pragma unroll
    for (int hd = 0; hd < 4; hd++) {
        float ss = 0.f, dd = 0.f;
#pragma unroll
        for (int c = 0; c < 16; c++) {
            float wv = W[(hd * 16 + c) * IN_CH + k];
            ss += a[hd * 32 + c] * wv;
            dd += a[hd * 32 + 16 + c] * wv;
        }
        Wh[(64 + hd) * IN_CH + k] = (_Float16)ss;
        Wh[(68 + hd) * IN_CH + k] = (_Float16)dd;
    }
}

__device__ inline f16x8 cvt8(const float* p) {
    float4 lo = ((const float4*)p)[0];
    float4 hi = ((const float4*)p)[1];
    f16x8 f;
    f[0] = (_Float16)lo.x; f[1] = (_Float16)lo.y;
    f[2] = (_Float16)lo.z; f[3] = (_Float16)lo.w;
    f[4] = (_Float16)hi.x; f[5] = (_Float16)hi.y;
    f[6] = (_Float16)hi.z; f[7] = (_Float16)hi.w;
    return f;
}

// ---------------------------------------------------------------------------
// GEMM v6 = v5 structure (128 nodes/block, bfrag held over 2 m-tiles,
// LDS-staged coalesced h epilogue) + direct f16 B loads from Wh (halves
// B bytes, kills ~160 cvt VALU/wave, cuts prologue register pressure).
// N-tile 4 carries alpha (rows 64-71; cols 0-3 = a_src heads, 4-7 = a_dst).
// ---------------------------------------------------------------------------
__global__ __launch_bounds__(256) void gemm_alpha_kernel(
    const float* __restrict__ x,      // [N_NODES, 128]
    const _Float16* __restrict__ Wh,  // [72, 128] f16
    _Float16* __restrict__ h,         // [N_NODES, 64] fp16
    float* __restrict__ alpha_src,    // [N_NODES, 4]
    float* __restrict__ alpha_dst)    // [N_NODES, 4]
{
    __shared__ _Float16 hst[128 * 72];   // stride 72: 16B rows, conflicts ~nil (R5)

    const int wv = threadIdx.x >> 6;
    const int lane = threadIdx.x & 63;
    const int col = lane & 15;
    const int quad = lane >> 4;
    const int node_base = blockIdx.x * 128 + wv * 32;

    f16x8 bfrag[5][4];
#pragma unroll
    for (int nt = 0; nt < 4; nt++) {
        const _Float16* src = Wh + (nt * 16 + col) * IN_CH;
#pragma unroll
        for (int ks = 0; ks < 4; ks++)
            bfrag[nt][ks] = *(const f16x8*)(src + ks * 32 + quad * 8);
    }
    {
        const _Float16* src = Wh + (64 + (col < 8 ? col : 0)) * IN_CH;
#pragma unroll
        for (int ks = 0; ks < 4; ks++) {
            f16x8 f = *(const f16x8*)(src + ks * 32 + quad * 8);
            if (col >= 8) {
                f16x8 z = {};
                f = z;
            }
            bfrag[4][ks] = f;
        }
    }

#pragma unroll
    for (int mt = 0; mt < 2; mt++) {
        int row_node = node_base + mt * 16 + col;
        int rn = row_node < N_NODES ? row_node : N_NODES - 1;
        const float* xrow = x + (long long)rn * IN_CH;

        f16x8 afrag[4];
#pragma unroll
        for (int ks = 0; ks < 4; ks++)
            afrag[ks] = cvt8(xrow + ks * 32 + quad * 8);

        f32x4 acc[5];
#pragma unroll
        for (int nt = 0; nt < 5; nt++) {
            f32x4 z = {0.f, 0.f, 0.f, 0.f};
            acc[nt] = z;
        }
#pragma unroll
        for (int ks = 0; ks < 4; ks++)
#pragma unroll
            for (int nt = 0; nt < 5; nt++)
                acc[nt] = __builtin_amdgcn_mfma_f32_16x16x32_f16(
                    afrag[ks], bfrag[nt][ks], acc[nt], 0, 0, 0);

#pragma unroll
        for (int r = 0; r < 4; r++) {
            int nl = wv * 32 + mt * 16 + quad * 4 + r;
#pragma unroll
            for (int nt = 0; nt < 4; nt++)
                hst[nl * 72 + nt * 16 + col] = (_Float16)acc[nt][r];
            int node = node_base + mt * 16 + quad * 4 + r;
            if (node < N_NODES) {
                if (col < 4)      alpha_src[node * HEADS + col]     = acc[4][r];
                else if (col < 8) alpha_dst[node * HEADS + col - 4] = acc[4][r];
            }
        }
    }

    // coalesced copy-out: 128 nodes x 64 ch fp16, 16B per lane
    __syncthreads();
    const int bnode = blockIdx.x * 128;
    const int nrem = N_NODES - bnode;
    const int climit = (nrem < 128 ? nrem : 128) << 3;   // f16x8 chunks
    for (int i = threadIdx.x; i < 1024; i += 256) {
        if (i < climit) {
            int node = i >> 3, ch8 = i & 7;
            *(f16x8*)(h + (long long)(bnode + node) * OUT_CH + ch8 * 8) =
                *(const f16x8*)&hst[node * 72 + ch8 * 8];
        }
    }
}

// ---------------------------------------------------------------------------
// CSR build: fused count+scatter with STATIC per-bucket regions.
//   512 blocks (was 256 = 1 block/CU = only 4 waves/CU to hide the
//   load->LDS-atomic->scatter chain; now 8 waves/CU). Reserve atomics
//   grow 100K->200K (~+4us at the 25G/s memory-side rate) -- net win.
// ---------------------------------------------------------------------------
__global__ __launch_bounds__(256) void fused_count_scatter_kernel(
    const int* __restrict__ ei, const float* __restrict__ ew,
    int* __restrict__ gcur,                 // [NBUCK] zeroed cursors
    unsigned long long* __restrict__ tmp)   // [NBUCK][CAPG]
{
    __shared__ int cnt[NBUCK];      // hist, then absolute cursors
    __shared__ int dbuf[CHUNK];     // 12.5 KB staged dst
    for (int j = threadIdx.x; j < NBUCK; j += 256) cnt[j] = 0;
    __syncthreads();
    const int base = blockIdx.x * CHUNK;
    for (int i = threadIdx.x; i < CHUNK; i += 256) {
        int d = ei[N_EDGES + base + i];
        dbuf[i] = d;
        atomicAdd(&cnt[d >> 8], 1);          // LDS atomic
    }
    __syncthreads();
    for (int j = threadIdx.x; j < NBUCK; j += 256) {
        int c = cnt[j];
        int b = (c > 0) ? atomicAdd(&gcur[j], c) : 0;   // global reserve
        cnt[j] = j * CAPG + b;               // absolute cursor into tmp
    }
    __syncthreads();
    for (int i = threadIdx.x; i < CHUNK; i += 256) {
        int e = base + i;
        int d = dbuf[i];
        int s = ei[e];
        float w = ew[e];
        int pos = atomicAdd(&cnt[d >> 8], 1);            // LDS atomic
        unsigned long long pk = ((unsigned long long)__float_as_uint(w) << 32)
                              | ((unsigned)(d & 255) << 17) | (unsigned)s;
        tmp[pos] = pk;   // per-(block,bucket) runs ~64B contiguous
    }
}

__global__ __launch_bounds__(512) void bucket_offsets_kernel(
    const int* __restrict__ gcur, int* __restrict__ bucketStart,
    int* __restrict__ ptr)
{
    __shared__ int part[512];
    const int t = threadIdx.x;
    int v = (t < NBUCK) ? gcur[t] : 0;
    part[t] = v;
    __syncthreads();
    for (int off = 1; off < 512; off <<= 1) {
        int x = (t >= off) ? part[t - off] : 0;
        __syncthreads();
        part[t] += x;
        __syncthreads();
    }
    if (t < NBUCK) bucketStart[t] = part[t] - v;     // exclusive
    if (t == 0) { bucketStart[NBUCK] = N_EDGES; ptr[N_NODES] = N_EDGES; }
}

// ---------------------------------------------------------------------------
// finalize v3: rank captured from the atomic RETURN in the staging pass
// (u16 per edge), so the placement pass is atomic-free: pos=offs[d]+rank.
// Halves LDS-atomic traffic vs v2.
// ---------------------------------------------------------------------------
__global__ __launch_bounds__(256) void finalize_kernel(
    const unsigned long long* __restrict__ tmp,
    const int* __restrict__ gcur,
    const int* __restrict__ bucketStart,
    long long* __restrict__ csr, int* __restrict__ ptr)
{
    __shared__ int cnt[256];
    __shared__ int offs[256];
    __shared__ unsigned short rk[CAP];
    __shared__ unsigned long long stage[CAP];
    const int j = blockIdx.x;
    const int t = threadIdx.x;
    const int beg = bucketStart[j];
    const int len = gcur[j];
    const unsigned long long* src = tmp + (size_t)j * CAPG;

    cnt[t] = 0;
    __syncthreads();

    // pass 1: stage + count + rank (single global read)
    for (int i = t; i < len; i += 256) {
        unsigned long long pk = __builtin_nontemporal_load(&src[i]);
        stage[i] = pk;
        rk[i] = (unsigned short)atomicAdd(&cnt[(int)((pk >> 17) & 255)], 1);
    }
    __syncthreads();
    int v = cnt[t];
    for (int off = 1; off < 256; off <<= 1) {   // inclusive scan
        int x = (t >= off) ? cnt[t - off] : 0;
        __syncthreads();
        cnt[t] += x;
        __syncthreads();
    }
    int excl = cnt[t] - v;
    int node = j * 256 + t;
    if (node < N_NODES) ptr[node] = beg + excl;
    offs[t] = excl;
    __syncthreads();
    // pass 2: atomic-free placement
    for (int i = t; i < len; i += 256) {
        unsigned long long pk = stage[i];
        int dloc = (int)((pk >> 17) & 255);
        int pos = offs[dloc] + (int)rk[i];
        unsigned long long vv = (pk & 0xFFFFFFFF00000000ull) | (pk & 0x1FFFFull);
        ((unsigned long long*)csr)[beg + pos] = vv;  // 32KB window, L2-combined
    }
}

// ---------------------------------------------------------------------------
// Aggregate v3 (control -- byte-identical to R7: ~46.5us, near the
// compulsory per-XCD L3->L2 fill bound of the random h gather).
// One wave per dst node, quarter-wave edge parallelism.
// ---------------------------------------------------------------------------
__global__ __launch_bounds__(256) void aggregate_kernel(
    const int* __restrict__ ptr,
    const int2* __restrict__ csr,
    const float4* __restrict__ alpha_src4,   // [N_NODES]
    const float4* __restrict__ alpha_dst4,   // [N_NODES]
    const _Float16* __restrict__ h,          // [N_NODES, 64]
    float* __restrict__ out)
{
    __shared__ float4 sev[4][64];   // per-wave ev4 staging
    __shared__ int    ssc[4][64];   // per-wave src staging

    const int wv = threadIdx.x >> 6;
    const int lane = threadIdx.x & 63;
    const int n = blockIdx.x * 4 + wv;
    if (n >= N_NODES) return;
    const int q = lane >> 4;          // quarter 0..3
    const int cg = lane & 15;         // channel group: ch 4*cg..4*cg+3
    const int hsel = cg >> 2;         // head of this channel group

    const int beg = ptr[n];
    const int end = ptr[n + 1];
    const float4 ad4 = alpha_dst4[n];

    float4 acc = make_float4(0.f, 0.f, 0.f, 0.f);
    float denom = 0.f;
    float4* sev_w = sev[wv];
    int* ssc_w = ssc[wv];

    for (int base = beg; base < end; base += 64) {
        int cnt = min(64, end - base);
        int s_l = 0;
        float4 e4 = make_float4(0.f, 0.f, 0.f, 0.f);
        if (lane < cnt) {
            int2 pr = csr[base + lane];
            s_l = pr.x;
            float w = __int_as_float(pr.y);
            float4 as = alpha_src4[s_l];
            float t0 = as.x + ad4.x; t0 = (t0 > 0.f ? t0 : NEG_SLOPE * t0) * w;
            float t1 = as.y + ad4.y; t1 = (t1 > 0.f ? t1 : NEG_SLOPE * t1) * w;
            float t2 = as.z + ad4.z; t2 = (t2 > 0.f ? t2 : NEG_SLOPE * t2) * w;
            float t3 = as.w + ad4.w; t3 = (t3 > 0.f ? t3 : NEG_SLOPE * t3) * w;
            e4 = make_float4(__expf(t0), __expf(t1), __expf(t2), __expf(t3));
        }
        sev_w[lane] = e4;         // intra-wave LDS, no barrier needed
        ssc_w[lane] = s_l;

        int iters = (cnt + 3) >> 2;
        for (int j0 = 0; j0 < iters; j0 += 2) {
            int idx0 = j0 * 4 + q;
            int idx1 = idx0 + 4;          // may pass cnt: contributes zero
            int s0 = ssc_w[idx0];
            int s1 = ssc_w[idx1];
            float ev0 = ((const float*)&sev_w[idx0])[hsel];
            float ev1 = ((const float*)&sev_w[idx1])[hsel];
            f16x4 h0 = *(const f16x4*)(h + s0 * OUT_CH + cg * 4);
            f16x4 h1 = *(const f16x4*)(h + s1 * OUT_CH + cg * 4);
            acc.x += ev0 * (float)h0[0] + ev1 * (float)h1[0];
            acc.y += ev0 * (float)h0[1] + ev1 * (float)h1[1];
            acc.z += ev0 * (float)h0[2] + ev1 * (float)h1[2];
            acc.w += ev0 * (float)h0[3] + ev1 * (float)h1[3];
            denom += ev0 + ev1;
        }
    }

    // combine the 4 quarters (xor butterfly)
    denom += __shfl_xor(denom, 16);
    denom += __shfl_xor(denom, 32);
    acc.x += __shfl_xor(acc.x, 16);  acc.x += __shfl_xor(acc.x, 32);
    acc.y += __shfl_xor(acc.y, 16);  acc.y += __shfl_xor(acc.y, 32);
    acc.z += __shfl_xor(acc.z, 16);  acc.z += __shfl_xor(acc.z, 32);
    acc.w += __shfl_xor(acc.w, 16);  acc.w += __shfl_xor(acc.w, 32);

    if (lane < 16) {
        float inv = 1.f / (denom + EPS);
        float4 r = make_float4(acc.x * inv, acc.y * inv, acc.z * inv, acc.w * inv);
        ((float4*)(out + (long long)n * OUT_CH))[cg] = r;
    }
}

extern "C" void kernel_launch(void* const* d_in, const int* in_sizes, int n_in,
                              void* d_out, int out_size, void* d_ws, size_t ws_size,
                              hipStream_t stream) {
    const float* x  = (const float*)d_in[0];
    const int*   ei = (const int*)d_in[1];     // int32 per harness contract
    const float* ew = (const float*)d_in[2];
    const float* W  = (const float*)d_in[3];
    const float* a  = (const float*)d_in[4];
    float* out = (float*)d_out;

    // workspace layout (all 16B-aligned); total ~43.7 MB
    char* p = (char*)d_ws;
    _Float16* h      = (_Float16*)p; p += (size_t)N_NODES * OUT_CH * 2;   // 12.8 MB
    float* alpha_src = (float*)p;  p += (size_t)N_NODES * HEADS * 4;      // 1.6 MB
    float* alpha_dst = (float*)p;  p += (size_t)N_NODES * HEADS * 4;      // 1.6 MB
    _Float16* Wh     = (_Float16*)p; p += (size_t)72 * IN_CH * 2;         // 18.4 KB
    int*   gcur      = (int*)p;    p += (size_t)392 * 4;                  // 1.6 KB
    int*   bstart    = (int*)p;    p += (size_t)392 * 4;                  // 1.6 KB
    int*   ptr       = (int*)p;    p += (size_t)(N_NODES + 4) * 4;        // 0.4 MB
    unsigned long long* tmp = (unsigned long long*)p;
    p += (size_t)NBUCK * CAPG * 8;                                        // 14.4 MB
    long long* csr   = (long long*)p;                                     // 12.8 MB

    hipMemsetAsync(gcur, 0, 392 * sizeof(int), stream);

    prep16_kernel<<<1, 128, 0, stream>>>(W, a, Wh);
    fused_count_scatter_kernel<<<NBLK1, 256, 0, stream>>>(ei, ew, gcur, tmp);
    bucket_offsets_kernel<<<1, 512, 0, stream>>>(gcur, bstart, ptr);
    gemm_alpha_kernel<<<(N_NODES + 127) / 128, 256, 0, stream>>>(x, Wh, h, alpha_src, alpha_dst);
    finalize_kernel<<<NBUCK, 256, 0, stream>>>(tmp, gcur, bstart, csr, ptr);
    aggregate_kernel<<<(N_NODES + 3) / 4, 256, 0, stream>>>(
        ptr, (const int2*)csr, (const float4*)alpha_src, (const float4*)alpha_dst, h, out);
}

// Round 9
// 205.263 us; speedup vs baseline: 1.3787x; 1.0279x over previous
//
#include <hip/hip_runtime.h>
#include <math.h>

#define N_NODES 100000
#define N_EDGES 1600000
#define IN_CH 128
#define HEADS 4
#define HEAD_DIM 16
#define OUT_CH 64
#define NEG_SLOPE 0.2f
#define EPS 1e-8f

// ---- counting-sort CSR build parameters ----
#define NBUCK 391                 // coarse buckets of 256 nodes: (100000+255)/256
#define NBLK1 512                 // fused pass blocks
#define CHUNK (N_EDGES / NBLK1)   // 3125 edges per block (exact)
#define CAPG 4608                 // static per-bucket region (mean 4092 + 8 sigma)
#define CAP CAPG

typedef _Float16 f16x8 __attribute__((ext_vector_type(8)));
typedef _Float16 f16x4 __attribute__((ext_vector_type(4)));
typedef float    f32x4 __attribute__((ext_vector_type(4)));

// XOR-swizzle for the LDS copy of Wh (row stride 256B): spreads the
// column-slice b128 reads across bank groups (2x fewer conflicts).
#define SWZ(b) ((b) ^ ((((b) >> 8) & 7) << 4))

// ---------------------------------------------------------------------------
// Prep: Wh[72][128] f16 — rows 0-63 = (f16)W, rows 64-67 = w_s, 68-71 = w_d.
// Also zeroes gcur (folds the old hipMemsetAsync dispatch).
// ---------------------------------------------------------------------------
__global__ __launch_bounds__(128) void prep16_kernel(
    const float* __restrict__ W, const float* __restrict__ a,
    _Float16* __restrict__ Wh, int* __restrict__ gcur)
{
    int k = threadIdx.x;   // 0..127
    for (int i = k; i < NBUCK + 1; i += 128) gcur[i] = 0;
#pragma unroll
    for (int r = 0; r < 64; r++)
        Wh[r * IN_CH + k] = (_Float16)W[r * IN_CH + k];
#pragma unroll
    for (int hd = 0; hd < 4; hd++) {
        float ss = 0.f, dd = 0.f;
#pragma unroll
        for (int c = 0; c < 16; c++) {
            float wv = W[(hd * 16 + c) * IN_CH + k];
            ss += a[hd * 32 + c] * wv;
            dd += a[hd * 32 + 16 + c] * wv;
        }
        Wh[(64 + hd) * IN_CH + k] = (_Float16)ss;
        Wh[(68 + hd) * IN_CH + k] = (_Float16)dd;
    }
}

__device__ inline f16x8 cvt8(const float* p) {
    float4 lo = ((const float4*)p)[0];
    float4 hi = ((const float4*)p)[1];
    f16x8 f;
    f[0] = (_Float16)lo.x; f[1] = (_Float16)lo.y;
    f[2] = (_Float16)lo.z; f[3] = (_Float16)lo.w;
    f[4] = (_Float16)hi.x; f[5] = (_Float16)hi.y;
    f[6] = (_Float16)hi.z; f[7] = (_Float16)hi.w;
    return f;
}

// ---------------------------------------------------------------------------
// GEMM v7: 512 threads = 8 waves, ONE 16-node m-tile per wave (128/block,
// 782 blocks -> 24 waves/CU grid vs v6's 12). Wh staged once per block into
// swizzled LDS; B-fragments STREAMED from LDS in the MFMA loop (transient
// 4 VGPR) instead of held (80 VGPR) -> low register pressure, high TLP.
// LDS-staged coalesced h epilogue kept from v5/v6.
// ---------------------------------------------------------------------------
__global__ __launch_bounds__(512, 6) void gemm_alpha_kernel(
    const float* __restrict__ x,      // [N_NODES, 128]
    const _Float16* __restrict__ Wh,  // [72, 128] f16
    _Float16* __restrict__ h,         // [N_NODES, 64] fp16
    float* __restrict__ alpha_src,    // [N_NODES, 4]
    float* __restrict__ alpha_dst)    // [N_NODES, 4]
{
    __shared__ _Float16 whs[72 * 128];   // 18.4 KB, swizzled
    __shared__ _Float16 hst[128 * 72];   // 18.4 KB, stride 72 (conflicts ~nil, R5)

    const int wv = threadIdx.x >> 6;     // 0..7
    const int lane = threadIdx.x & 63;
    const int col = lane & 15;
    const int quad = lane >> 4;

    // stage Wh -> LDS (swizzled), 1152 x 16B chunks over 512 threads
    for (int c = threadIdx.x; c < 1152; c += 512) {
        int b = c << 4;
        *(f16x8*)((char*)whs + SWZ(b)) = *(const f16x8*)((const char*)Wh + b);
    }
    __syncthreads();

    const int node_base = blockIdx.x * 128 + wv * 16;
    int row_node = node_base + col;
    int rn = row_node < N_NODES ? row_node : N_NODES - 1;
    const float* xrow = x + (long long)rn * IN_CH;

    f16x8 afrag[4];
#pragma unroll
    for (int ks = 0; ks < 4; ks++)
        afrag[ks] = cvt8(xrow + ks * 32 + quad * 8);

    f32x4 acc[5];
#pragma unroll
    for (int nt = 0; nt < 5; nt++) {
        f32x4 z = {0.f, 0.f, 0.f, 0.f};
        acc[nt] = z;
    }

#pragma unroll
    for (int ks = 0; ks < 4; ks++) {
#pragma unroll
        for (int nt = 0; nt < 5; nt++) {
            int r = (nt < 4) ? nt * 16 + col : 64 + (col & 7);
            int b = (r << 8) + (ks << 6) + (quad << 4);
            f16x8 bf = *(const f16x8*)((const char*)whs + SWZ(b));
            if (nt == 4 && col >= 8) {
                f16x8 z = {};
                bf = z;
            }
            acc[nt] = __builtin_amdgcn_mfma_f32_16x16x32_f16(
                afrag[ks], bf, acc[nt], 0, 0, 0);
        }
    }

#pragma unroll
    for (int r = 0; r < 4; r++) {
        int nl = wv * 16 + quad * 4 + r;
#pragma unroll
        for (int nt = 0; nt < 4; nt++)
            hst[nl * 72 + nt * 16 + col] = (_Float16)acc[nt][r];
        int node = node_base + quad * 4 + r;
        if (node < N_NODES) {
            if (col < 4)      alpha_src[node * HEADS + col]     = acc[4][r];
            else if (col < 8) alpha_dst[node * HEADS + col - 4] = acc[4][r];
        }
    }

    // coalesced copy-out: 128 nodes x 64 ch fp16, 16B per lane
    __syncthreads();
    const int bnode = blockIdx.x * 128;
    const int nrem = N_NODES - bnode;
    const int climit = (nrem < 128 ? nrem : 128) << 3;   // f16x8 chunks
    for (int i = threadIdx.x; i < 1024; i += 512) {
        if (i < climit) {
            int node = i >> 3, ch8 = i & 7;
            *(f16x8*)(h + (long long)(bnode + node) * OUT_CH + ch8 * 8) =
                *(const f16x8*)&hst[node * 72 + ch8 * 8];
        }
    }
}

// ---------------------------------------------------------------------------
// CSR build: fused count+scatter with STATIC per-bucket regions.
// 512 threads x 512 blocks = 16 waves/CU (was 8) to hide the
// load->LDS-atomic->scatter chain. Reserve atomics unchanged (200K).
// ---------------------------------------------------------------------------
__global__ __launch_bounds__(512) void fused_count_scatter_kernel(
    const int* __restrict__ ei, const float* __restrict__ ew,
    int* __restrict__ gcur,                 // [NBUCK] zeroed cursors
    unsigned long long* __restrict__ tmp)   // [NBUCK][CAPG]
{
    __shared__ int cnt[NBUCK];      // hist, then absolute cursors
    __shared__ int dbuf[CHUNK];     // 12.5 KB staged dst
    for (int j = threadIdx.x; j < NBUCK; j += 512) cnt[j] = 0;
    __syncthreads();
    const int base = blockIdx.x * CHUNK;
    for (int i = threadIdx.x; i < CHUNK; i += 512) {
        int d = ei[N_EDGES + base + i];
        dbuf[i] = d;
        atomicAdd(&cnt[d >> 8], 1);          // LDS atomic
    }
    __syncthreads();
    for (int j = threadIdx.x; j < NBUCK; j += 512) {
        int c = cnt[j];
        int b = (c > 0) ? atomicAdd(&gcur[j], c) : 0;   // global reserve
        cnt[j] = j * CAPG + b;               // absolute cursor into tmp
    }
    __syncthreads();
    for (int i = threadIdx.x; i < CHUNK; i += 512) {
        int e = base + i;
        int d = dbuf[i];
        int s = ei[e];
        float w = ew[e];
        int pos = atomicAdd(&cnt[d >> 8], 1);            // LDS atomic
        unsigned long long pk = ((unsigned long long)__float_as_uint(w) << 32)
                              | ((unsigned)(d & 255) << 17) | (unsigned)s;
        tmp[pos] = pk;   // per-(block,bucket) runs ~64B contiguous
    }
}

__global__ __launch_bounds__(512) void bucket_offsets_kernel(
    const int* __restrict__ gcur, int* __restrict__ bucketStart,
    int* __restrict__ ptr)
{
    __shared__ int part[512];
    const int t = threadIdx.x;
    int v = (t < NBUCK) ? gcur[t] : 0;
    part[t] = v;
    __syncthreads();
    for (int off = 1; off < 512; off <<= 1) {
        int x = (t >= off) ? part[t - off] : 0;
        __syncthreads();
        part[t] += x;
        __syncthreads();
    }
    if (t < NBUCK) bucketStart[t] = part[t] - v;     // exclusive
    if (t == 0) { bucketStart[NBUCK] = N_EDGES; ptr[N_NODES] = N_EDGES; }
}

// ---------------------------------------------------------------------------
// finalize v4: 512 threads (12 waves/CU avg vs 6 at 256 -- this kernel has
// only 391 blocks, so per-block TLP is the only lever). Rank from atomic
// return (pass 2 atomic-free) kept from v3.
// ---------------------------------------------------------------------------
__global__ __launch_bounds__(512) void finalize_kernel(
    const unsigned long long* __restrict__ tmp,
    const int* __restrict__ gcur,
    const int* __restrict__ bucketStart,
    long long* __restrict__ csr, int* __restrict__ ptr)
{
    __shared__ int cnt[256];
    __shared__ int offs[256];
    __shared__ unsigned short rk[CAP];
    __shared__ unsigned long long stage[CAP];
    const int j = blockIdx.x;
    const int t = threadIdx.x;
    const int beg = bucketStart[j];
    const int len = gcur[j];
    const unsigned long long* src = tmp + (size_t)j * CAPG;

    if (t < 256) cnt[t] = 0;
    __syncthreads();

    // pass 1: stage + count + rank (single global read)
    for (int i = t; i < len; i += 512) {
        unsigned long long pk = __builtin_nontemporal_load(&src[i]);
        stage[i] = pk;
        rk[i] = (unsigned short)atomicAdd(&cnt[(int)((pk >> 17) & 255)], 1);
    }
    __syncthreads();
    int v = (t < 256) ? cnt[t] : 0;
    for (int off = 1; off < 256; off <<= 1) {   // inclusive scan (t<256 active)
        int x = (t < 256 && t >= off) ? cnt[t - off] : 0;
        __syncthreads();
        if (t < 256) cnt[t] += x;
        __syncthreads();
    }
    if (t < 256) {
        int excl = cnt[t] - v;
        int node = j * 256 + t;
        if (node < N_NODES) ptr[node] = beg + excl;
        offs[t] = excl;
    }
    __syncthreads();
    // pass 2: atomic-free placement
    for (int i = t; i < len; i += 512) {
        unsigned long long pk = stage[i];
        int dloc = (int)((pk >> 17) & 255);
        int pos = offs[dloc] + (int)rk[i];
        unsigned long long vv = (pk & 0xFFFFFFFF00000000ull) | (pk & 0x1FFFFull);
        ((unsigned long long*)csr)[beg + pos] = vv;  // 32KB window, L2-combined
    }
}

// ---------------------------------------------------------------------------
// Aggregate v3 (control -- byte-identical: ~45.7us, ~1.15x the compulsory
// per-XCD L3->L2 fill of the random h gather; confirmed at its bound).
// One wave per dst node, quarter-wave edge parallelism.
// ---------------------------------------------------------------------------
__global__ __launch_bounds__(256) void aggregate_kernel(
    const int* __restrict__ ptr,
    const int2* __restrict__ csr,
    const float4* __restrict__ alpha_src4,   // [N_NODES]
    const float4* __restrict__ alpha_dst4,   // [N_NODES]
    const _Float16* __restrict__ h,          // [N_NODES, 64]
    float* __restrict__ out)
{
    __shared__ float4 sev[4][64];   // per-wave ev4 staging
    __shared__ int    ssc[4][64];   // per-wave src staging

    const int wv = threadIdx.x >> 6;
    const int lane = threadIdx.x & 63;
    const int n = blockIdx.x * 4 + wv;
    if (n >= N_NODES) return;
    const int q = lane >> 4;          // quarter 0..3
    const int cg = lane & 15;         // channel group: ch 4*cg..4*cg+3
    const int hsel = cg >> 2;         // head of this channel group

    const int beg = ptr[n];
    const int end = ptr[n + 1];
    const float4 ad4 = alpha_dst4[n];

    float4 acc = make_float4(0.f, 0.f, 0.f, 0.f);
    float denom = 0.f;
    float4* sev_w = sev[wv];
    int* ssc_w = ssc[wv];

    for (int base = beg; base < end; base += 64) {
        int cnt = min(64, end - base);
        int s_l = 0;
        float4 e4 = make_float4(0.f, 0.f, 0.f, 0.f);
        if (lane < cnt) {
            int2 pr = csr[base + lane];
            s_l = pr.x;
            float w = __int_as_float(pr.y);
            float4 as = alpha_src4[s_l];
            float t0 = as.x + ad4.x; t0 = (t0 > 0.f ? t0 : NEG_SLOPE * t0) * w;
            float t1 = as.y + ad4.y; t1 = (t1 > 0.f ? t1 : NEG_SLOPE * t1) * w;
            float t2 = as.z + ad4.z; t2 = (t2 > 0.f ? t2 : NEG_SLOPE * t2) * w;
            float t3 = as.w + ad4.w; t3 = (t3 > 0.f ? t3 : NEG_SLOPE * t3) * w;
            e4 = make_float4(__expf(t0), __expf(t1), __expf(t2), __expf(t3));
        }
        sev_w[lane] = e4;         // intra-wave LDS, no barrier needed
        ssc_w[lane] = s_l;

        int iters = (cnt + 3) >> 2;
        for (int j0 = 0; j0 < iters; j0 += 2) {
            int idx0 = j0 * 4 + q;
            int idx1 = idx0 + 4;          // may pass cnt: contributes zero
            int s0 = ssc_w[idx0];
            int s1 = ssc_w[idx1];
            float ev0 = ((const float*)&sev_w[idx0])[hsel];
            float ev1 = ((const float*)&sev_w[idx1])[hsel];
            f16x4 h0 = *(const f16x4*)(h + s0 * OUT_CH + cg * 4);
            f16x4 h1 = *(const f16x4*)(h + s1 * OUT_CH + cg * 4);
            acc.x += ev0 * (float)h0[0] + ev1 * (float)h1[0];
            acc.y += ev0 * (float)h0[1] + ev1 * (float)h1[1];
            acc.z += ev0 * (float)h0[2] + ev1 * (float)h1[2];
            acc.w += ev0 * (float)h0[3] + ev1 * (float)h1[3];
            denom += ev0 + ev1;
        }
    }

    // combine the 4 quarters (xor butterfly)
    denom += __shfl_xor(denom, 16);
    denom += __shfl_xor(denom, 32);
    acc.x += __shfl_xor(acc.x, 16);  acc.x += __shfl_xor(acc.x, 32);
    acc.y += __shfl_xor(acc.y, 16);  acc.y += __shfl_xor(acc.y, 32);
    acc.z += __shfl_xor(acc.z, 16);  acc.z += __shfl_xor(acc.z, 32);
    acc.w += __shfl_xor(acc.w, 16);  acc.w += __shfl_xor(acc.w, 32);

    if (lane < 16) {
        float inv = 1.f / (denom + EPS);
        float4 r = make_float4(acc.x * inv, acc.y * inv, acc.z * inv, acc.w * inv);
        ((float4*)(out + (long long)n * OUT_CH))[cg] = r;
    }
}

extern "C" void kernel_launch(void* const* d_in, const int* in_sizes, int n_in,
                              void* d_out, int out_size, void* d_ws, size_t ws_size,
                              hipStream_t stream) {
    const float* x  = (const float*)d_in[0];
    const int*   ei = (const int*)d_in[1];     // int32 per harness contract
    const float* ew = (const float*)d_in[2];
    const float* W  = (const float*)d_in[3];
    const float* a  = (const float*)d_in[4];
    float* out = (float*)d_out;

    // workspace layout (all 16B-aligned); total ~43.7 MB
    char* p = (char*)d_ws;
    _Float16* h      = (_Float16*)p; p += (size_t)N_NODES * OUT_CH * 2;   // 12.8 MB
    float* alpha_src = (float*)p;  p += (size_t)N_NODES * HEADS * 4;      // 1.6 MB
    float* alpha_dst = (float*)p;  p += (size_t)N_NODES * HEADS * 4;      // 1.6 MB
    _Float16* Wh     = (_Float16*)p; p += (size_t)72 * IN_CH * 2;         // 18.4 KB
    int*   gcur      = (int*)p;    p += (size_t)392 * 4;                  // 1.6 KB
    int*   bstart    = (int*)p;    p += (size_t)392 * 4;                  // 1.6 KB
    int*   ptr       = (int*)p;    p += (size_t)(N_NODES + 4) * 4;        // 0.4 MB
    unsigned long long* tmp = (unsigned long long*)p;
    p += (size_t)NBUCK * CAPG * 8;                                        // 14.4 MB
    long long* csr   = (long long*)p;                                     // 12.8 MB

    prep16_kernel<<<1, 128, 0, stream>>>(W, a, Wh, gcur);
    fused_count_scatter_kernel<<<NBLK1, 512, 0, stream>>>(ei, ew, gcur, tmp);
    bucket_offsets_kernel<<<1, 512, 0, stream>>>(gcur, bstart, ptr);
    gemm_alpha_kernel<<<(N_NODES + 127) / 128, 512, 0, stream>>>(x, Wh, h, alpha_src, alpha_dst);
    finalize_kernel<<<NBUCK, 512, 0, stream>>>(tmp, gcur, bstart, csr, ptr);
    aggregate_kernel<<<(N_NODES + 3) / 4, 256, 0, stream>>>(
        ptr, (const int2*)csr, (const float4*)alpha_src, (const float4*)alpha_dst, h, out);
}

// Round 10
// 193.043 us; speedup vs baseline: 1.4660x; 1.0633x over previous
//
#include <hip/hip_runtime.h>
#include <math.h>

#define N_NODES 100000
#define N_EDGES 1600000
#define IN_CH 128
#define HEADS 4
#define HEAD_DIM 16
#define OUT_CH 64
#define NEG_SLOPE 0.2f
#define EPS 1e-8f

// ---- counting-sort CSR build parameters ----
#define NBUCK 391                 // coarse buckets of 256 nodes: (100000+255)/256
#define NBLK1 512                 // scatter-role blocks
#define CHUNK (N_EDGES / NBLK1)   // 3125 edges per block (exact)
#define CAPG 4608                 // static per-bucket region (mean 4092 + 8 sigma)
#define CAP CAPG
#define GEMM_BLOCKS ((N_NODES + 127) / 128)   // 782
#define FAT_BLOCKS (NBLK1 + GEMM_BLOCKS)      // 1294

typedef _Float16 f16x8 __attribute__((ext_vector_type(8)));
typedef _Float16 f16x4 __attribute__((ext_vector_type(4)));
typedef float    f32x4 __attribute__((ext_vector_type(4)));

// XOR-swizzle for the LDS copy of Wh (row stride 256B): spreads the
// column-slice b128 reads across bank groups. XOR touches only bits 4-6,
// so sub-16B offsets are preserved (single-f16 stores compose with it).
#define SWZ(b) ((b) ^ ((((b) >> 8) & 7) << 4))

__device__ inline f16x8 cvt8(const float* p) {
    float4 lo = ((const float4*)p)[0];
    float4 hi = ((const float4*)p)[1];
    f16x8 f;
    f[0] = (_Float16)lo.x; f[1] = (_Float16)lo.y;
    f[2] = (_Float16)lo.z; f[3] = (_Float16)lo.w;
    f[4] = (_Float16)hi.x; f[5] = (_Float16)hi.y;
    f[6] = (_Float16)hi.z; f[7] = (_Float16)hi.w;
    return f;
}

// ---------------------------------------------------------------------------
// FAT kernel: blocks 0..511 = scatter role (CSR bucket sort, LDS atomics);
// blocks 512..1293 = gemm role (MFMA h + alpha). Roles are data-independent;
// co-residency overlaps the MFMA/x-latency pipe with the LDS-atomic/VMEM
// pipe (m114: co-scheduled waves run at ~max, not sum). Replaces prep16 +
// fused_count_scatter + gemm_alpha (2 launches + 1 serial 1-block kernel).
// ---------------------------------------------------------------------------
__global__ __launch_bounds__(512, 6) void gemm_scatter_kernel(
    const float* __restrict__ x,      // [N_NODES, 128]
    const float* __restrict__ W,      // [64, 128]
    const float* __restrict__ a,      // [1, 4, 32]
    const int* __restrict__ ei,
    const float* __restrict__ ew,
    int* __restrict__ gcur,                 // [NBUCK] zeroed cursors
    unsigned long long* __restrict__ tmp,   // [NBUCK][CAPG]
    _Float16* __restrict__ h,         // [N_NODES, 64] fp16
    float* __restrict__ alpha_src,    // [N_NODES, 4]
    float* __restrict__ alpha_dst)    // [N_NODES, 4]
{
    __shared__ __align__(16) char smem[36864];

    if (blockIdx.x < NBLK1) {
        // ================= scatter role =================
        int* cnt  = (int*)smem;               // [NBUCK] hist, then abs cursors
        int* dbuf = (int*)(smem + 1664);      // [CHUNK] staged dst
        for (int j = threadIdx.x; j < NBUCK; j += 512) cnt[j] = 0;
        __syncthreads();
        const int base = blockIdx.x * CHUNK;
        for (int i = threadIdx.x; i < CHUNK; i += 512) {
            int d = ei[N_EDGES + base + i];
            dbuf[i] = d;
            atomicAdd(&cnt[d >> 8], 1);          // LDS atomic
        }
        __syncthreads();
        for (int j = threadIdx.x; j < NBUCK; j += 512) {
            int c = cnt[j];
            int b = (c > 0) ? atomicAdd(&gcur[j], c) : 0;   // global reserve
            cnt[j] = j * CAPG + b;               // absolute cursor into tmp
        }
        __syncthreads();
        for (int i = threadIdx.x; i < CHUNK; i += 512) {
            int e = base + i;
            int d = dbuf[i];
            int s = ei[e];
            float w = ew[e];
            int pos = atomicAdd(&cnt[d >> 8], 1);            // LDS atomic
            unsigned long long pk = ((unsigned long long)__float_as_uint(w) << 32)
                                  | ((unsigned)(d & 255) << 17) | (unsigned)s;
            tmp[pos] = pk;   // per-(block,bucket) runs ~64B contiguous
        }
    } else {
        // ================= gemm role =================
        _Float16* whs = (_Float16*)smem;              // [72][128] swizzled
        _Float16* hst = (_Float16*)(smem + 18432);    // [128][72]

        const int gb = blockIdx.x - NBLK1;
        const int wv = threadIdx.x >> 6;     // 0..7
        const int lane = threadIdx.x & 63;
        const int col = lane & 15;
        const int quad = lane >> 4;

        // stage (f16)W rows 0-63 (cooperative cvt; W stays L2-hot)
        for (int i = threadIdx.x; i < 1024; i += 512) {
            int row = i >> 4, koff = (i & 15) << 3;
            int b = (row << 8) + (koff << 1);
            *(f16x8*)((char*)whs + SWZ(b)) = cvt8(W + row * IN_CH + koff);
        }
        // compute a.W rows 64-71 cooperatively (1024 elems x 16 FMA;
        // NOT the R5 serial-per-lane version)
        for (int i = threadIdx.x; i < 1024; i += 512) {
            int r8 = i >> 7, k = i & 127;
            int hd = r8 & 3, half = r8 >> 2;       // 0=src(rows 64-67), 1=dst
            const float* av = a + hd * 32 + half * 16;
            const float* wb = W + hd * 16 * IN_CH + k;
            float s = 0.f;
#pragma unroll
            for (int c = 0; c < 16; c++)
                s += av[c] * wb[c * IN_CH];
            int b = ((64 + r8) << 8) + (k << 1);
            *(_Float16*)((char*)whs + SWZ(b)) = (_Float16)s;
        }
        __syncthreads();

        const int node_base = gb * 128 + wv * 16;
        int row_node = node_base + col;
        int rn = row_node < N_NODES ? row_node : N_NODES - 1;
        const float* xrow = x + (long long)rn * IN_CH;

        f16x8 afrag[4];
#pragma unroll
        for (int ks = 0; ks < 4; ks++)
            afrag[ks] = cvt8(xrow + ks * 32 + quad * 8);

        f32x4 acc[5];
#pragma unroll
        for (int nt = 0; nt < 5; nt++) {
            f32x4 z = {0.f, 0.f, 0.f, 0.f};
            acc[nt] = z;
        }

#pragma unroll
        for (int ks = 0; ks < 4; ks++) {
#pragma unroll
            for (int nt = 0; nt < 5; nt++) {
                int r = (nt < 4) ? nt * 16 + col : 64 + (col & 7);
                int b = (r << 8) + (ks << 6) + (quad << 4);
                f16x8 bf = *(const f16x8*)((const char*)whs + SWZ(b));
                if (nt == 4 && col >= 8) {
                    f16x8 z = {};
                    bf = z;
                }
                acc[nt] = __builtin_amdgcn_mfma_f32_16x16x32_f16(
                    afrag[ks], bf, acc[nt], 0, 0, 0);
            }
        }

#pragma unroll
        for (int r = 0; r < 4; r++) {
            int nl = wv * 16 + quad * 4 + r;
#pragma unroll
            for (int nt = 0; nt < 4; nt++)
                hst[nl * 72 + nt * 16 + col] = (_Float16)acc[nt][r];
            int node = node_base + quad * 4 + r;
            if (node < N_NODES) {
                if (col < 4)      alpha_src[node * HEADS + col]     = acc[4][r];
                else if (col < 8) alpha_dst[node * HEADS + col - 4] = acc[4][r];
            }
        }

        // coalesced copy-out: 128 nodes x 64 ch fp16, 16B per lane
        __syncthreads();
        const int bnode = gb * 128;
        const int nrem = N_NODES - bnode;
        const int climit = (nrem < 128 ? nrem : 128) << 3;   // f16x8 chunks
        for (int i = threadIdx.x; i < 1024; i += 512) {
            if (i < climit) {
                int node = i >> 3, ch8 = i & 7;
                *(f16x8*)(h + (long long)(bnode + node) * OUT_CH + ch8 * 8) =
                    *(const f16x8*)&hst[node * 72 + ch8 * 8];
            }
        }
    }
}

// ---------------------------------------------------------------------------
// finalize v5: per-block exclusive prefix of gcur in LDS (removes the
// serial 1-block bucket_offsets launch; 512-wide scan over L2-hot gcur is
// ~trivial). Rank-from-atomic-return placement kept (pass 2 atomic-free).
// ---------------------------------------------------------------------------
__global__ __launch_bounds__(512) void finalize_kernel(
    const unsigned long long* __restrict__ tmp,
    const int* __restrict__ gcur,
    long long* __restrict__ csr, int* __restrict__ ptr)
{
    __shared__ int cnt[256];
    __shared__ int offs[256];
    __shared__ int scanbuf[512];
    __shared__ unsigned short rk[CAP];
    __shared__ unsigned long long stage[CAP];
    const int j = blockIdx.x;
    const int t = threadIdx.x;

    // exclusive prefix of gcur -> beg/len for this bucket
    int gv = (t < NBUCK) ? gcur[t] : 0;
    scanbuf[t] = gv;
    if (t < 256) cnt[t] = 0;
    __syncthreads();
    for (int off = 1; off < 512; off <<= 1) {
        int xx = (t >= off) ? scanbuf[t - off] : 0;
        __syncthreads();
        scanbuf[t] += xx;
        __syncthreads();
    }
    const int incl = scanbuf[j];
    const int beg  = (j > 0) ? scanbuf[j - 1] : 0;
    const int len  = incl - beg;
    if (j == 0 && t == 0) ptr[N_NODES] = N_EDGES;
    const unsigned long long* src = tmp + (size_t)j * CAPG;

    // pass 1: stage + count + rank (single global read)
    for (int i = t; i < len; i += 512) {
        unsigned long long pk = __builtin_nontemporal_load(&src[i]);
        stage[i] = pk;
        rk[i] = (unsigned short)atomicAdd(&cnt[(int)((pk >> 17) & 255)], 1);
    }
    __syncthreads();
    int v = (t < 256) ? cnt[t] : 0;
    for (int off = 1; off < 256; off <<= 1) {   // inclusive scan (t<256 active)
        int xx = (t < 256 && t >= off) ? cnt[t - off] : 0;
        __syncthreads();
        if (t < 256) cnt[t] += xx;
        __syncthreads();
    }
    if (t < 256) {
        int excl = cnt[t] - v;
        int node = j * 256 + t;
        if (node < N_NODES) ptr[node] = beg + excl;
        offs[t] = excl;
    }
    __syncthreads();
    // pass 2: atomic-free placement
    for (int i = t; i < len; i += 512) {
        unsigned long long pk = stage[i];
        int dloc = (int)((pk >> 17) & 255);
        int pos = offs[dloc] + (int)rk[i];
        unsigned long long vv = (pk & 0xFFFFFFFF00000000ull) | (pk & 0x1FFFFull);
        ((unsigned long long*)csr)[beg + pos] = vv;  // 32KB window, L2-combined
    }
}

// ---------------------------------------------------------------------------
// Aggregate v3 (control -- byte-identical: ~46us, ~1.15x the compulsory
// per-XCD L3->L2 fill of the random h gather; confirmed at its bound).
// One wave per dst node, quarter-wave edge parallelism.
// ---------------------------------------------------------------------------
__global__ __launch_bounds__(256) void aggregate_kernel(
    const int* __restrict__ ptr,
    const int2* __restrict__ csr,
    const float4* __restrict__ alpha_src4,   // [N_NODES]
    const float4* __restrict__ alpha_dst4,   // [N_NODES]
    const _Float16* __restrict__ h,          // [N_NODES, 64]
    float* __restrict__ out)
{
    __shared__ float4 sev[4][64];   // per-wave ev4 staging
    __shared__ int    ssc[4][64];   // per-wave src staging

    const int wv = threadIdx.x >> 6;
    const int lane = threadIdx.x & 63;
    const int n = blockIdx.x * 4 + wv;
    if (n >= N_NODES) return;
    const int q = lane >> 4;          // quarter 0..3
    const int cg = lane & 15;         // channel group: ch 4*cg..4*cg+3
    const int hsel = cg >> 2;         // head of this channel group

    const int beg = ptr[n];
    const int end = ptr[n + 1];
    const float4 ad4 = alpha_dst4[n];

    float4 acc = make_float4(0.f, 0.f, 0.f, 0.f);
    float denom = 0.f;
    float4* sev_w = sev[wv];
    int* ssc_w = ssc[wv];

    for (int base = beg; base < end; base += 64) {
        int cnt = min(64, end - base);
        int s_l = 0;
        float4 e4 = make_float4(0.f, 0.f, 0.f, 0.f);
        if (lane < cnt) {
            int2 pr = csr[base + lane];
            s_l = pr.x;
            float w = __int_as_float(pr.y);
            float4 as = alpha_src4[s_l];
            float t0 = as.x + ad4.x; t0 = (t0 > 0.f ? t0 : NEG_SLOPE * t0) * w;
            float t1 = as.y + ad4.y; t1 = (t1 > 0.f ? t1 : NEG_SLOPE * t1) * w;
            float t2 = as.z + ad4.z; t2 = (t2 > 0.f ? t2 : NEG_SLOPE * t2) * w;
            float t3 = as.w + ad4.w; t3 = (t3 > 0.f ? t3 : NEG_SLOPE * t3) * w;
            e4 = make_float4(__expf(t0), __expf(t1), __expf(t2), __expf(t3));
        }
        sev_w[lane] = e4;         // intra-wave LDS, no barrier needed
        ssc_w[lane] = s_l;

        int iters = (cnt + 3) >> 2;
        for (int j0 = 0; j0 < iters; j0 += 2) {
            int idx0 = j0 * 4 + q;
            int idx1 = idx0 + 4;          // may pass cnt: contributes zero
            int s0 = ssc_w[idx0];
            int s1 = ssc_w[idx1];
            float ev0 = ((const float*)&sev_w[idx0])[hsel];
            float ev1 = ((const float*)&sev_w[idx1])[hsel];
            f16x4 h0 = *(const f16x4*)(h + s0 * OUT_CH + cg * 4);
            f16x4 h1 = *(const f16x4*)(h + s1 * OUT_CH + cg * 4);
            acc.x += ev0 * (float)h0[0] + ev1 * (float)h1[0];
            acc.y += ev0 * (float)h0[1] + ev1 * (float)h1[1];
            acc.z += ev0 * (float)h0[2] + ev1 * (float)h1[2];
            acc.w += ev0 * (float)h0[3] + ev1 * (float)h1[3];
            denom += ev0 + ev1;
        }
    }

    // combine the 4 quarters (xor butterfly)
    denom += __shfl_xor(denom, 16);
    denom += __shfl_xor(denom, 32);
    acc.x += __shfl_xor(acc.x, 16);  acc.x += __shfl_xor(acc.x, 32);
    acc.y += __shfl_xor(acc.y, 16);  acc.y += __shfl_xor(acc.y, 32);
    acc.z += __shfl_xor(acc.z, 16);  acc.z += __shfl_xor(acc.z, 32);
    acc.w += __shfl_xor(acc.w, 16);  acc.w += __shfl_xor(acc.w, 32);

    if (lane < 16) {
        float inv = 1.f / (denom + EPS);
        float4 r = make_float4(acc.x * inv, acc.y * inv, acc.z * inv, acc.w * inv);
        ((float4*)(out + (long long)n * OUT_CH))[cg] = r;
    }
}

extern "C" void kernel_launch(void* const* d_in, const int* in_sizes, int n_in,
                              void* d_out, int out_size, void* d_ws, size_t ws_size,
                              hipStream_t stream) {
    const float* x  = (const float*)d_in[0];
    const int*   ei = (const int*)d_in[1];     // int32 per harness contract
    const float* ew = (const float*)d_in[2];
    const float* W  = (const float*)d_in[3];
    const float* a  = (const float*)d_in[4];
    float* out = (float*)d_out;

    // workspace layout (all 16B-aligned); total ~43.7 MB
    char* p = (char*)d_ws;
    _Float16* h      = (_Float16*)p; p += (size_t)N_NODES * OUT_CH * 2;   // 12.8 MB
    float* alpha_src = (float*)p;  p += (size_t)N_NODES * HEADS * 4;      // 1.6 MB
    float* alpha_dst = (float*)p;  p += (size_t)N_NODES * HEADS * 4;      // 1.6 MB
    int*   gcur      = (int*)p;    p += (size_t)400 * 4;                  // 1.6 KB
    int*   ptr       = (int*)p;    p += (size_t)(N_NODES + 4) * 4;        // 0.4 MB
    unsigned long long* tmp = (unsigned long long*)p;
    p += (size_t)NBUCK * CAPG * 8;                                        // 14.4 MB
    long long* csr   = (long long*)p;                                     // 12.8 MB

    hipMemsetAsync(gcur, 0, 400 * sizeof(int), stream);

    gemm_scatter_kernel<<<FAT_BLOCKS, 512, 0, stream>>>(
        x, W, a, ei, ew, gcur, tmp, h, alpha_src, alpha_dst);
    finalize_kernel<<<NBUCK, 512, 0, stream>>>(tmp, gcur, csr, ptr);
    aggregate_kernel<<<(N_NODES + 3) / 4, 256, 0, stream>>>(
        ptr, (const int2*)csr, (const float4*)alpha_src, (const float4*)alpha_dst, h, out);
}

// Round 11
// 191.468 us; speedup vs baseline: 1.4781x; 1.0082x over previous
//
#include <hip/hip_runtime.h>
#include <math.h>

#define N_NODES 100000
#define N_EDGES 1600000
#define IN_CH 128
#define HEADS 4
#define HEAD_DIM 16
#define OUT_CH 64
#define NEG_SLOPE 0.2f
#define EPS 1e-8f

// ---- counting-sort CSR build parameters ----
#define NBUCK 391                 // coarse buckets of 256 nodes: (100000+255)/256
#define NBLK1 512                 // scatter-role blocks
#define CHUNK (N_EDGES / NBLK1)   // 3125 edges per block (exact)
#define CAPG 4608                 // static per-bucket region (mean 4092 + 8 sigma)
#define CAPH 2560                 // half-bucket LDS bound (mean 2048 + >10 sigma)
#define GEMM_BLOCKS ((N_NODES + 127) / 128)   // 782
#define FAT_BLOCKS (NBLK1 + GEMM_BLOCKS)      // 1294

typedef _Float16 f16x8 __attribute__((ext_vector_type(8)));
typedef _Float16 f16x4 __attribute__((ext_vector_type(4)));
typedef float    f32x4 __attribute__((ext_vector_type(4)));

// XOR-swizzle for the LDS copy of Wh (row stride 256B): spreads the
// column-slice b128 reads across bank groups. XOR touches only bits 4-6,
// so sub-16B offsets are preserved (single-f16 stores compose with it).
#define SWZ(b) ((b) ^ ((((b) >> 8) & 7) << 4))

__device__ inline f16x8 cvt8(const float* p) {
    float4 lo = ((const float4*)p)[0];
    float4 hi = ((const float4*)p)[1];
    f16x8 f;
    f[0] = (_Float16)lo.x; f[1] = (_Float16)lo.y;
    f[2] = (_Float16)lo.z; f[3] = (_Float16)lo.w;
    f[4] = (_Float16)hi.x; f[5] = (_Float16)hi.y;
    f[6] = (_Float16)hi.z; f[7] = (_Float16)hi.w;
    return f;
}

// ---------------------------------------------------------------------------
// FAT kernel (control -- byte-identical to R10): blocks 0..511 = scatter
// role (CSR bucket sort, LDS atomics); blocks 512..1293 = gemm role (MFMA
// h + alpha). Roles data-independent; co-residency overlaps pipes.
// ---------------------------------------------------------------------------
__global__ __launch_bounds__(512, 6) void gemm_scatter_kernel(
    const float* __restrict__ x,      // [N_NODES, 128]
    const float* __restrict__ W,      // [64, 128]
    const float* __restrict__ a,      // [1, 4, 32]
    const int* __restrict__ ei,
    const float* __restrict__ ew,
    int* __restrict__ gcur,                 // [NBUCK] zeroed cursors
    unsigned long long* __restrict__ tmp,   // [NBUCK][CAPG]
    _Float16* __restrict__ h,         // [N_NODES, 64] fp16
    float* __restrict__ alpha_src,    // [N_NODES, 4]
    float* __restrict__ alpha_dst)    // [N_NODES, 4]
{
    __shared__ __align__(16) char smem[36864];

    if (blockIdx.x < NBLK1) {
        // ================= scatter role =================
        int* cnt  = (int*)smem;               // [NBUCK] hist, then abs cursors
        int* dbuf = (int*)(smem + 1664);      // [CHUNK] staged dst
        for (int j = threadIdx.x; j < NBUCK; j += 512) cnt[j] = 0;
        __syncthreads();
        const int base = blockIdx.x * CHUNK;
        for (int i = threadIdx.x; i < CHUNK; i += 512) {
            int d = ei[N_EDGES + base + i];
            dbuf[i] = d;
            atomicAdd(&cnt[d >> 8], 1);          // LDS atomic
        }
        __syncthreads();
        for (int j = threadIdx.x; j < NBUCK; j += 512) {
            int c = cnt[j];
            int b = (c > 0) ? atomicAdd(&gcur[j], c) : 0;   // global reserve
            cnt[j] = j * CAPG + b;               // absolute cursor into tmp
        }
        __syncthreads();
        for (int i = threadIdx.x; i < CHUNK; i += 512) {
            int e = base + i;
            int d = dbuf[i];
            int s = ei[e];
            float w = ew[e];
            int pos = atomicAdd(&cnt[d >> 8], 1);            // LDS atomic
            unsigned long long pk = ((unsigned long long)__float_as_uint(w) << 32)
                                  | ((unsigned)(d & 255) << 17) | (unsigned)s;
            tmp[pos] = pk;   // per-(block,bucket) runs ~64B contiguous
        }
    } else {
        // ================= gemm role =================
        _Float16* whs = (_Float16*)smem;              // [72][128] swizzled
        _Float16* hst = (_Float16*)(smem + 18432);    // [128][72]

        const int gb = blockIdx.x - NBLK1;
        const int wv = threadIdx.x >> 6;     // 0..7
        const int lane = threadIdx.x & 63;
        const int col = lane & 15;
        const int quad = lane >> 4;

        // stage (f16)W rows 0-63 (cooperative cvt; W stays L2-hot)
        for (int i = threadIdx.x; i < 1024; i += 512) {
            int row = i >> 4, koff = (i & 15) << 3;
            int b = (row << 8) + (koff << 1);
            *(f16x8*)((char*)whs + SWZ(b)) = cvt8(W + row * IN_CH + koff);
        }
        // compute a.W rows 64-71 cooperatively (1024 elems x 16 FMA)
        for (int i = threadIdx.x; i < 1024; i += 512) {
            int r8 = i >> 7, k = i & 127;
            int hd = r8 & 3, half = r8 >> 2;       // 0=src(rows 64-67), 1=dst
            const float* av = a + hd * 32 + half * 16;
            const float* wb = W + hd * 16 * IN_CH + k;
            float s = 0.f;
#pragma unroll
            for (int c = 0; c < 16; c++)
                s += av[c] * wb[c * IN_CH];
            int b = ((64 + r8) << 8) + (k << 1);
            *(_Float16*)((char*)whs + SWZ(b)) = (_Float16)s;
        }
        __syncthreads();

        const int node_base = gb * 128 + wv * 16;
        int row_node = node_base + col;
        int rn = row_node < N_NODES ? row_node : N_NODES - 1;
        const float* xrow = x + (long long)rn * IN_CH;

        f16x8 afrag[4];
#pragma unroll
        for (int ks = 0; ks < 4; ks++)
            afrag[ks] = cvt8(xrow + ks * 32 + quad * 8);

        f32x4 acc[5];
#pragma unroll
        for (int nt = 0; nt < 5; nt++) {
            f32x4 z = {0.f, 0.f, 0.f, 0.f};
            acc[nt] = z;
        }

#pragma unroll
        for (int ks = 0; ks < 4; ks++) {
#pragma unroll
            for (int nt = 0; nt < 5; nt++) {
                int r = (nt < 4) ? nt * 16 + col : 64 + (col & 7);
                int b = (r << 8) + (ks << 6) + (quad << 4);
                f16x8 bf = *(const f16x8*)((const char*)whs + SWZ(b));
                if (nt == 4 && col >= 8) {
                    f16x8 z = {};
                    bf = z;
                }
                acc[nt] = __builtin_amdgcn_mfma_f32_16x16x32_f16(
                    afrag[ks], bf, acc[nt], 0, 0, 0);
            }
        }

#pragma unroll
        for (int r = 0; r < 4; r++) {
            int nl = wv * 16 + quad * 4 + r;
#pragma unroll
            for (int nt = 0; nt < 4; nt++)
                hst[nl * 72 + nt * 16 + col] = (_Float16)acc[nt][r];
            int node = node_base + quad * 4 + r;
            if (node < N_NODES) {
                if (col < 4)      alpha_src[node * HEADS + col]     = acc[4][r];
                else if (col < 8) alpha_dst[node * HEADS + col - 4] = acc[4][r];
            }
        }

        // coalesced copy-out: 128 nodes x 64 ch fp16, 16B per lane
        __syncthreads();
        const int bnode = gb * 128;
        const int nrem = N_NODES - bnode;
        const int climit = (nrem < 128 ? nrem : 128) << 3;   // f16x8 chunks
        for (int i = threadIdx.x; i < 1024; i += 512) {
            if (i < climit) {
                int node = i >> 3, ch8 = i & 7;
                *(f16x8*)(h + (long long)(bnode + node) * OUT_CH + ch8 * 8) =
                    *(const f16x8*)&hst[node * 72 + ch8 * 8];
            }
        }
    }
}

// ---------------------------------------------------------------------------
// group_aggregate: finalize FUSED into aggregate -- csr/ptr never
// materialized (saves ~25MB of HBM round-trip + one launch boundary).
// 2 blocks per bucket, each owning 128 nodes. Pass 1: count own-half
// per-node over the bucket's tmp region. Scan 128 counters. Pass 2
// (L2-hot re-read): place own-half edges node-grouped into LDS.
// Then the PROVEN aggregate inner loop (quarter-wave edge parallelism)
// runs per local node, sourcing (s,w) from LDS instead of global csr.
// LDS ~31.5KB -> 4 blocks/CU cap; grid 782 = 3.05/CU fully resident.
// ---------------------------------------------------------------------------
__global__ __launch_bounds__(512) void group_aggregate_kernel(
    const unsigned long long* __restrict__ tmp,
    const int* __restrict__ gcur,
    const float4* __restrict__ alpha_src4,   // [N_NODES]
    const float4* __restrict__ alpha_dst4,   // [N_NODES]
    const _Float16* __restrict__ h,          // [N_NODES, 64]
    float* __restrict__ out)
{
    __shared__ int cntA[128];                 // per-local-node degree
    __shared__ int baseA[128];                // exclusive prefix (fixed)
    __shared__ int curA[128];                 // pass-2 cursors
    __shared__ unsigned long long grouped[CAPH];
    __shared__ float4 sev[8][64];
    __shared__ int    ssc[8][64];

    const int j = blockIdx.x >> 1;            // bucket
    const int half = blockIdx.x & 1;          // which 128-node half
    const int t = threadIdx.x;
    const int len = min(gcur[j], CAPG);
    const unsigned long long* src = tmp + (size_t)j * CAPG;

    if (t < 128) cntA[t] = 0;
    __syncthreads();

    // pass 1: count own-half edges per node
    for (int i = t; i < len; i += 512) {
        int dloc = (int)((src[i] >> 17) & 255);
        if ((dloc >> 7) == half) atomicAdd(&cntA[dloc & 127], 1);
    }
    __syncthreads();
    if (t < 128) curA[t] = cntA[t];
    __syncthreads();
    for (int off = 1; off < 128; off <<= 1) {   // inclusive scan (t<128)
        int xx = (t < 128 && t >= off) ? curA[t - off] : 0;
        __syncthreads();
        if (t < 128) curA[t] += xx;
        __syncthreads();
    }
    if (t < 128) { baseA[t] = curA[t] - cntA[t]; curA[t] = baseA[t]; }
    __syncthreads();
    // pass 2: node-grouped placement (re-read is L2-hot)
    for (int i = t; i < len; i += 512) {
        unsigned long long pk = src[i];
        int dloc = (int)((pk >> 17) & 255);
        if ((dloc >> 7) == half) {
            int pos = atomicAdd(&curA[dloc & 127], 1);
            if (pos < CAPH) grouped[pos] = pk;   // >10-sigma guard
        }
    }
    __syncthreads();

    // aggregation (same structure as the proven aggregate v3)
    const int wv = t >> 6;
    const int lane = t & 63;
    const int q = lane >> 4;          // quarter 0..3
    const int cg = lane & 15;         // channel group
    const int hsel = cg >> 2;         // head of this channel group
    float4* sev_w = sev[wv];
    int* ssc_w = ssc[wv];

    for (int nl = wv; nl < 128; nl += 8) {       // wave-uniform node id
        int n = j * 256 + half * 128 + nl;
        if (n >= N_NODES) continue;
        int ebeg = baseA[nl];
        int deg = cntA[nl];
        if (ebeg + deg > CAPH) deg = (CAPH > ebeg) ? CAPH - ebeg : 0;
        const float4 ad4 = alpha_dst4[n];

        float4 acc = make_float4(0.f, 0.f, 0.f, 0.f);
        float denom = 0.f;

        for (int b0 = 0; b0 < deg; b0 += 64) {
            int cnt_e = min(64, deg - b0);
            int s_l = 0;
            float4 e4 = make_float4(0.f, 0.f, 0.f, 0.f);
            if (lane < cnt_e) {
                unsigned long long pk = grouped[ebeg + b0 + lane];
                s_l = (int)(pk & 0x1FFFF);
                float w = __int_as_float((int)(pk >> 32));
                float4 as = alpha_src4[s_l];
                float t0 = as.x + ad4.x; t0 = (t0 > 0.f ? t0 : NEG_SLOPE * t0) * w;
                float t1 = as.y + ad4.y; t1 = (t1 > 0.f ? t1 : NEG_SLOPE * t1) * w;
                float t2 = as.z + ad4.z; t2 = (t2 > 0.f ? t2 : NEG_SLOPE * t2) * w;
                float t3 = as.w + ad4.w; t3 = (t3 > 0.f ? t3 : NEG_SLOPE * t3) * w;
                e4 = make_float4(__expf(t0), __expf(t1), __expf(t2), __expf(t3));
            }
            sev_w[lane] = e4;         // intra-wave LDS, no barrier needed
            ssc_w[lane] = s_l;

            int iters = (cnt_e + 3) >> 2;
            for (int j0 = 0; j0 < iters; j0 += 2) {
                int idx0 = j0 * 4 + q;
                int idx1 = idx0 + 4;          // may pass cnt_e: contributes zero
                int s0 = ssc_w[idx0];
                int s1 = ssc_w[idx1];
                float ev0 = ((const float*)&sev_w[idx0])[hsel];
                float ev1 = ((const float*)&sev_w[idx1])[hsel];
                f16x4 h0 = *(const f16x4*)(h + s0 * OUT_CH + cg * 4);
                f16x4 h1 = *(const f16x4*)(h + s1 * OUT_CH + cg * 4);
                acc.x += ev0 * (float)h0[0] + ev1 * (float)h1[0];
                acc.y += ev0 * (float)h0[1] + ev1 * (float)h1[1];
                acc.z += ev0 * (float)h0[2] + ev1 * (float)h1[2];
                acc.w += ev0 * (float)h0[3] + ev1 * (float)h1[3];
                denom += ev0 + ev1;
            }
        }

        // combine the 4 quarters (xor butterfly)
        denom += __shfl_xor(denom, 16);
        denom += __shfl_xor(denom, 32);
        acc.x += __shfl_xor(acc.x, 16);  acc.x += __shfl_xor(acc.x, 32);
        acc.y += __shfl_xor(acc.y, 16);  acc.y += __shfl_xor(acc.y, 32);
        acc.z += __shfl_xor(acc.z, 16);  acc.z += __shfl_xor(acc.z, 32);
        acc.w += __shfl_xor(acc.w, 16);  acc.w += __shfl_xor(acc.w, 32);

        if (lane < 16) {
            float inv = 1.f / (denom + EPS);
            float4 r = make_float4(acc.x * inv, acc.y * inv, acc.z * inv, acc.w * inv);
            ((float4*)(out + (long long)n * OUT_CH))[cg] = r;
        }
    }
}

extern "C" void kernel_launch(void* const* d_in, const int* in_sizes, int n_in,
                              void* d_out, int out_size, void* d_ws, size_t ws_size,
                              hipStream_t stream) {
    const float* x  = (const float*)d_in[0];
    const int*   ei = (const int*)d_in[1];     // int32 per harness contract
    const float* ew = (const float*)d_in[2];
    const float* W  = (const float*)d_in[3];
    const float* a  = (const float*)d_in[4];
    float* out = (float*)d_out;

    // workspace layout (all 16B-aligned); total ~31 MB
    char* p = (char*)d_ws;
    _Float16* h      = (_Float16*)p; p += (size_t)N_NODES * OUT_CH * 2;   // 12.8 MB
    float* alpha_src = (float*)p;  p += (size_t)N_NODES * HEADS * 4;      // 1.6 MB
    float* alpha_dst = (float*)p;  p += (size_t)N_NODES * HEADS * 4;      // 1.6 MB
    int*   gcur      = (int*)p;    p += (size_t)400 * 4;                  // 1.6 KB
    unsigned long long* tmp = (unsigned long long*)p;                     // 14.4 MB

    hipMemsetAsync(gcur, 0, 400 * sizeof(int), stream);

    gemm_scatter_kernel<<<FAT_BLOCKS, 512, 0, stream>>>(
        x, W, a, ei, ew, gcur, tmp, h, alpha_src, alpha_dst);
    group_aggregate_kernel<<<NBUCK * 2, 512, 0, stream>>>(
        tmp, gcur, (const float4*)alpha_src, (const float4*)alpha_dst, h, out);
}

// Round 12
// 185.678 us; speedup vs baseline: 1.5242x; 1.0312x over previous
//
#include <hip/hip_runtime.h>
#include <math.h>

#define N_NODES 100000
#define N_EDGES 1600000
#define IN_CH 128
#define HEADS 4
#define HEAD_DIM 16
#define OUT_CH 64
#define NEG_SLOPE 0.2f
#define EPS 1e-8f

// ---- counting-sort CSR build parameters ----
#define NBUCK 391                 // coarse buckets of 256 nodes: (100000+255)/256
#define NBLK1 512                 // scatter-role blocks
#define CHUNK (N_EDGES / NBLK1)   // 3125 edges per block (exact)
#define CAPG 4608                 // static per-bucket region (mean 4092 + 8 sigma)
#define CAPH 2560                 // half-bucket LDS bound (mean 2048 + >10 sigma)
#define GEMM_TILES ((N_NODES + 127) / 128)    // 782 tiles of 128 nodes
#define GEMM_BLKS 512                          // gemm-role blocks (grid-stride tiles)
#define FAT_BLOCKS (NBLK1 + GEMM_BLKS)         // 1024 = 4/CU exactly, no tail round

typedef _Float16 f16x8 __attribute__((ext_vector_type(8)));
typedef _Float16 f16x4 __attribute__((ext_vector_type(4)));
typedef float    f32x4 __attribute__((ext_vector_type(4)));

// XOR-swizzle for the LDS copy of Wh (row stride 256B): spreads the
// column-slice b128 reads across bank groups. XOR touches only bits 4-6,
// so sub-16B offsets are preserved (single-f16 stores compose with it).
#define SWZ(b) ((b) ^ ((((b) >> 8) & 7) << 4))

__device__ inline f16x8 cvt8(const float* p) {
    float4 lo = ((const float4*)p)[0];
    float4 hi = ((const float4*)p)[1];
    f16x8 f;
    f[0] = (_Float16)lo.x; f[1] = (_Float16)lo.y;
    f[2] = (_Float16)lo.z; f[3] = (_Float16)lo.w;
    f[4] = (_Float16)hi.x; f[5] = (_Float16)hi.y;
    f[6] = (_Float16)hi.z; f[7] = (_Float16)hi.w;
    return f;
}

// ---------------------------------------------------------------------------
// FAT kernel v2: blocks 0..511 = scatter role; blocks 512..1023 = gemm role
// grid-striding over 782 tiles (1024 blocks = exactly 4/CU at the 32-wave
// cap -- R10's 1294-block grid had a 270-block second scheduling round at
// ~26% utilization). Scatter pass 1 now stages src/w/dst in LDS (3 coalesced
// streams), so the atomic-scatter loop has zero exposed global reads.
// ---------------------------------------------------------------------------
__global__ __launch_bounds__(512, 6) void gemm_scatter_kernel(
    const float* __restrict__ x,      // [N_NODES, 128]
    const float* __restrict__ W,      // [64, 128]
    const float* __restrict__ a,      // [1, 4, 32]
    const int* __restrict__ ei,
    const float* __restrict__ ew,
    int* __restrict__ gcur,                 // [NBUCK] zeroed cursors
    unsigned long long* __restrict__ tmp,   // [NBUCK][CAPG]
    _Float16* __restrict__ h,         // [N_NODES, 64] fp16
    float* __restrict__ alpha_src,    // [N_NODES, 4]
    float* __restrict__ alpha_dst)    // [N_NODES, 4]
{
    __shared__ __align__(16) char smem[40960];   // 4 x 40KB = 160KB/CU exactly

    if (blockIdx.x < NBLK1) {
        // ================= scatter role =================
        int*   cnt  = (int*)smem;                  // [NBUCK] hist -> abs cursors
        int*   dbuf = (int*)(smem + 1664);         // [CHUNK] staged dst
        int*   sbuf = (int*)(smem + 14164);        // [CHUNK] staged src
        float* wbuf = (float*)(smem + 26664);      // [CHUNK] staged w
        for (int j = threadIdx.x; j < NBUCK; j += 512) cnt[j] = 0;
        __syncthreads();
        const int base = blockIdx.x * CHUNK;
        for (int i = threadIdx.x; i < CHUNK; i += 512) {
            int d = ei[N_EDGES + base + i];
            int s = ei[base + i];
            float w = ew[base + i];
            dbuf[i] = d;
            sbuf[i] = s;
            wbuf[i] = w;
            atomicAdd(&cnt[d >> 8], 1);          // LDS atomic
        }
        __syncthreads();
        for (int j = threadIdx.x; j < NBUCK; j += 512) {
            int c = cnt[j];
            int b = (c > 0) ? atomicAdd(&gcur[j], c) : 0;   // global reserve
            cnt[j] = j * CAPG + b;               // absolute cursor into tmp
        }
        __syncthreads();
        for (int i = threadIdx.x; i < CHUNK; i += 512) {
            int d = dbuf[i];
            int pos = atomicAdd(&cnt[d >> 8], 1);            // LDS atomic
            unsigned long long pk =
                ((unsigned long long)__float_as_uint(wbuf[i]) << 32)
                | ((unsigned)(d & 255) << 17) | (unsigned)sbuf[i];
            tmp[pos] = pk;   // per-(block,bucket) runs ~64B contiguous
        }
    } else {
        // ================= gemm role =================
        _Float16* whs = (_Float16*)smem;              // [72][128] swizzled
        _Float16* hst = (_Float16*)(smem + 18432);    // [128][72]

        const int gb = blockIdx.x - NBLK1;
        const int wv = threadIdx.x >> 6;     // 0..7
        const int lane = threadIdx.x & 63;
        const int col = lane & 15;
        const int quad = lane >> 4;

        // stage (f16)W rows 0-63 (cooperative cvt; W stays L2-hot)
        for (int i = threadIdx.x; i < 1024; i += 512) {
            int row = i >> 4, koff = (i & 15) << 3;
            int b = (row << 8) + (koff << 1);
            *(f16x8*)((char*)whs + SWZ(b)) = cvt8(W + row * IN_CH + koff);
        }
        // compute a.W rows 64-71 cooperatively (1024 elems x 16 FMA)
        for (int i = threadIdx.x; i < 1024; i += 512) {
            int r8 = i >> 7, k = i & 127;
            int hd = r8 & 3, half = r8 >> 2;       // 0=src(rows 64-67), 1=dst
            const float* av = a + hd * 32 + half * 16;
            const float* wb = W + hd * 16 * IN_CH + k;
            float s = 0.f;
#pragma unroll
            for (int c = 0; c < 16; c++)
                s += av[c] * wb[c * IN_CH];
            int b = ((64 + r8) << 8) + (k << 1);
            *(_Float16*)((char*)whs + SWZ(b)) = (_Float16)s;
        }
        __syncthreads();

        // grid-stride over tiles: W staging amortized across 1-2 tiles/block
        for (int tile = gb; tile < GEMM_TILES; tile += GEMM_BLKS) {
            const int node_base = tile * 128 + wv * 16;
            int row_node = node_base + col;
            int rn = row_node < N_NODES ? row_node : N_NODES - 1;
            const float* xrow = x + (long long)rn * IN_CH;

            f16x8 afrag[4];
#pragma unroll
            for (int ks = 0; ks < 4; ks++)
                afrag[ks] = cvt8(xrow + ks * 32 + quad * 8);

            f32x4 acc[5];
#pragma unroll
            for (int nt = 0; nt < 5; nt++) {
                f32x4 z = {0.f, 0.f, 0.f, 0.f};
                acc[nt] = z;
            }

#pragma unroll
            for (int ks = 0; ks < 4; ks++) {
#pragma unroll
                for (int nt = 0; nt < 5; nt++) {
                    int r = (nt < 4) ? nt * 16 + col : 64 + (col & 7);
                    int b = (r << 8) + (ks << 6) + (quad << 4);
                    f16x8 bf = *(const f16x8*)((const char*)whs + SWZ(b));
                    if (nt == 4 && col >= 8) {
                        f16x8 z = {};
                        bf = z;
                    }
                    acc[nt] = __builtin_amdgcn_mfma_f32_16x16x32_f16(
                        afrag[ks], bf, acc[nt], 0, 0, 0);
                }
            }

#pragma unroll
            for (int r = 0; r < 4; r++) {
                int nl = wv * 16 + quad * 4 + r;
#pragma unroll
                for (int nt = 0; nt < 4; nt++)
                    hst[nl * 72 + nt * 16 + col] = (_Float16)acc[nt][r];
                int node = node_base + quad * 4 + r;
                if (node < N_NODES) {
                    if (col < 4)      alpha_src[node * HEADS + col]     = acc[4][r];
                    else if (col < 8) alpha_dst[node * HEADS + col - 4] = acc[4][r];
                }
            }

            // coalesced copy-out: 128 nodes x 64 ch fp16, 16B per lane
            __syncthreads();
            const int bnode = tile * 128;
            const int nrem = N_NODES - bnode;
            const int climit = (nrem < 128 ? nrem : 128) << 3;   // f16x8 chunks
            for (int i = threadIdx.x; i < 1024; i += 512) {
                if (i < climit) {
                    int node = i >> 3, ch8 = i & 7;
                    *(f16x8*)(h + (long long)(bnode + node) * OUT_CH + ch8 * 8) =
                        *(const f16x8*)&hst[node * 72 + ch8 * 8];
                }
            }
            __syncthreads();   // protect hst before next tile overwrites
        }
    }
}

// ---------------------------------------------------------------------------
// group_aggregate (control -- byte-identical to R11): finalize fused into
// aggregate; csr/ptr never materialized. 2 blocks per bucket (128 nodes
// each); LDS node-grouping then the proven quarter-wave aggregation loop.
// ---------------------------------------------------------------------------
__global__ __launch_bounds__(512) void group_aggregate_kernel(
    const unsigned long long* __restrict__ tmp,
    const int* __restrict__ gcur,
    const float4* __restrict__ alpha_src4,   // [N_NODES]
    const float4* __restrict__ alpha_dst4,   // [N_NODES]
    const _Float16* __restrict__ h,          // [N_NODES, 64]
    float* __restrict__ out)
{
    __shared__ int cntA[128];                 // per-local-node degree
    __shared__ int baseA[128];                // exclusive prefix (fixed)
    __shared__ int curA[128];                 // pass-2 cursors
    __shared__ unsigned long long grouped[CAPH];
    __shared__ float4 sev[8][64];
    __shared__ int    ssc[8][64];

    const int j = blockIdx.x >> 1;            // bucket
    const int half = blockIdx.x & 1;          // which 128-node half
    const int t = threadIdx.x;
    const int len = min(gcur[j], CAPG);
    const unsigned long long* src = tmp + (size_t)j * CAPG;

    if (t < 128) cntA[t] = 0;
    __syncthreads();

    // pass 1: count own-half edges per node
    for (int i = t; i < len; i += 512) {
        int dloc = (int)((src[i] >> 17) & 255);
        if ((dloc >> 7) == half) atomicAdd(&cntA[dloc & 127], 1);
    }
    __syncthreads();
    if (t < 128) curA[t] = cntA[t];
    __syncthreads();
    for (int off = 1; off < 128; off <<= 1) {   // inclusive scan (t<128)
        int xx = (t < 128 && t >= off) ? curA[t - off] : 0;
        __syncthreads();
        if (t < 128) curA[t] += xx;
        __syncthreads();
    }
    if (t < 128) { baseA[t] = curA[t] - cntA[t]; curA[t] = baseA[t]; }
    __syncthreads();
    // pass 2: node-grouped placement (re-read is L2-hot)
    for (int i = t; i < len; i += 512) {
        unsigned long long pk = src[i];
        int dloc = (int)((pk >> 17) & 255);
        if ((dloc >> 7) == half) {
            int pos = atomicAdd(&curA[dloc & 127], 1);
            if (pos < CAPH) grouped[pos] = pk;   // >10-sigma guard
        }
    }
    __syncthreads();

    // aggregation (same structure as the proven aggregate v3)
    const int wv = t >> 6;
    const int lane = t & 63;
    const int q = lane >> 4;          // quarter 0..3
    const int cg = lane & 15;         // channel group
    const int hsel = cg >> 2;         // head of this channel group
    float4* sev_w = sev[wv];
    int* ssc_w = ssc[wv];

    for (int nl = wv; nl < 128; nl += 8) {       // wave-uniform node id
        int n = j * 256 + half * 128 + nl;
        if (n >= N_NODES) continue;
        int ebeg = baseA[nl];
        int deg = cntA[nl];
        if (ebeg + deg > CAPH) deg = (CAPH > ebeg) ? CAPH - ebeg : 0;
        const float4 ad4 = alpha_dst4[n];

        float4 acc = make_float4(0.f, 0.f, 0.f, 0.f);
        float denom = 0.f;

        for (int b0 = 0; b0 < deg; b0 += 64) {
            int cnt_e = min(64, deg - b0);
            int s_l = 0;
            float4 e4 = make_float4(0.f, 0.f, 0.f, 0.f);
            if (lane < cnt_e) {
                unsigned long long pk = grouped[ebeg + b0 + lane];
                s_l = (int)(pk & 0x1FFFF);
                float w = __int_as_float((int)(pk >> 32));
                float4 as = alpha_src4[s_l];
                float t0 = as.x + ad4.x; t0 = (t0 > 0.f ? t0 : NEG_SLOPE * t0) * w;
                float t1 = as.y + ad4.y; t1 = (t1 > 0.f ? t1 : NEG_SLOPE * t1) * w;
                float t2 = as.z + ad4.z; t2 = (t2 > 0.f ? t2 : NEG_SLOPE * t2) * w;
                float t3 = as.w + ad4.w; t3 = (t3 > 0.f ? t3 : NEG_SLOPE * t3) * w;
                e4 = make_float4(__expf(t0), __expf(t1), __expf(t2), __expf(t3));
            }
            sev_w[lane] = e4;         // intra-wave LDS, no barrier needed
            ssc_w[lane] = s_l;

            int iters = (cnt_e + 3) >> 2;
            for (int j0 = 0; j0 < iters; j0 += 2) {
                int idx0 = j0 * 4 + q;
                int idx1 = idx0 + 4;          // may pass cnt_e: contributes zero
                int s0 = ssc_w[idx0];
                int s1 = ssc_w[idx1];
                float ev0 = ((const float*)&sev_w[idx0])[hsel];
                float ev1 = ((const float*)&sev_w[idx1])[hsel];
                f16x4 h0 = *(const f16x4*)(h + s0 * OUT_CH + cg * 4);
                f16x4 h1 = *(const f16x4*)(h + s1 * OUT_CH + cg * 4);
                acc.x += ev0 * (float)h0[0] + ev1 * (float)h1[0];
                acc.y += ev0 * (float)h0[1] + ev1 * (float)h1[1];
                acc.z += ev0 * (float)h0[2] + ev1 * (float)h1[2];
                acc.w += ev0 * (float)h0[3] + ev1 * (float)h1[3];
                denom += ev0 + ev1;
            }
        }

        // combine the 4 quarters (xor butterfly)
        denom += __shfl_xor(denom, 16);
        denom += __shfl_xor(denom, 32);
        acc.x += __shfl_xor(acc.x, 16);  acc.x += __shfl_xor(acc.x, 32);
        acc.y += __shfl_xor(acc.y, 16);  acc.y += __shfl_xor(acc.y, 32);
        acc.z += __shfl_xor(acc.z, 16);  acc.z += __shfl_xor(acc.z, 32);
        acc.w += __shfl_xor(acc.w, 16);  acc.w += __shfl_xor(acc.w, 32);

        if (lane < 16) {
            float inv = 1.f / (denom + EPS);
            float4 r = make_float4(acc.x * inv, acc.y * inv, acc.z * inv, acc.w * inv);
            ((float4*)(out + (long long)n * OUT_CH))[cg] = r;
        }
    }
}

extern "C" void kernel_launch(void* const* d_in, const int* in_sizes, int n_in,
                              void* d_out, int out_size, void* d_ws, size_t ws_size,
                              hipStream_t stream) {
    const float* x  = (const float*)d_in[0];
    const int*   ei = (const int*)d_in[1];     // int32 per harness contract
    const float* ew = (const float*)d_in[2];
    const float* W  = (const float*)d_in[3];
    const float* a  = (const float*)d_in[4];
    float* out = (float*)d_out;

    // workspace layout (all 16B-aligned); total ~31 MB
    char* p = (char*)d_ws;
    _Float16* h      = (_Float16*)p; p += (size_t)N_NODES * OUT_CH * 2;   // 12.8 MB
    float* alpha_src = (float*)p;  p += (size_t)N_NODES * HEADS * 4;      // 1.6 MB
    float* alpha_dst = (float*)p;  p += (size_t)N_NODES * HEADS * 4;      // 1.6 MB
    int*   gcur      = (int*)p;    p += (size_t)400 * 4;                  // 1.6 KB
    unsigned long long* tmp = (unsigned long long*)p;                     // 14.4 MB

    hipMemsetAsync(gcur, 0, 400 * sizeof(int), stream);

    gemm_scatter_kernel<<<FAT_BLOCKS, 512, 0, stream>>>(
        x, W, a, ei, ew, gcur, tmp, h, alpha_src, alpha_dst);
    group_aggregate_kernel<<<NBUCK * 2, 512, 0, stream>>>(
        tmp, gcur, (const float4*)alpha_src, (const float4*)alpha_dst, h, out);
}